// Round 10
// baseline (341.361 us; speedup 1.0000x reference)
//
#include <hip/hip_runtime.h>
#include <hip/hip_fp16.h>
#include <math.h>

#ifndef INT_MAX
#define INT_MAX 0x7fffffff
#endif

typedef __attribute__((ext_vector_type(8))) _Float16 f16x8;
typedef __attribute__((ext_vector_type(4))) float   f32x4;

// ---------------------------------------------------------------------------
// Round 8 -> 9: register-prefetch pipelines (proj2..proj5, 245-295us) are all
// defeated by HIP regalloc (VGPR stuck at 64-104 -> load-dest reuse ->
// waitcnt serialization). proj6 switches to the m97-proven structure:
// global_load_lds A-staging (no VGPR dest -> deep in-flight window), LDS
// double buffer, 1 barrier per K-step. Lane->(px,k) staging map makes LDS
// px-major so each MFMA A-fragment is 2 contiguous ds_read_b128.
// ---------------------------------------------------------------------------

#define GLD4(src, dst)                                                        \
    __builtin_amdgcn_global_load_lds(                                         \
        (const __attribute__((address_space(1))) unsigned int*)(const void*)(src), \
        (__attribute__((address_space(3))) unsigned int*)(void*)(dst), 4, 0, 0)

__device__ __forceinline__ float gelu_exact(float x) {
    return 0.5f * x * (1.0f + erff(x * 0.70710678118654752f));
}

// ---- build_wt3: W3/4/5 -> fp16 fragment-order WF; transpose W1/W2 ----------
// WF layout (halves): WF[((t*256 + d)*4 + lg)*8 + j] = W[d][t*32 + lg*8 + j]
__global__ __launch_bounds__(256)
void build_wt3_kernel(const float* __restrict__ W3, const float* __restrict__ W4,
                      const float* __restrict__ W5, const float* __restrict__ W1,
                      const float* __restrict__ W2,
                      __half* __restrict__ WF3, __half* __restrict__ WF4,
                      __half* __restrict__ WF5,
                      float* __restrict__ W1T, float* __restrict__ W2T)
{
    const int bidx = blockIdx.x;
    const int tid  = threadIdx.x;
    if (bidx < 448) {
        const int c = bidx * 256 + tid;
        const float* Wsrc; __half* dst; int K, c0;
        if (c < 16384)      { Wsrc = W3; dst = WF3; K = 512;  c0 = c; }
        else if (c < 49152) { Wsrc = W4; dst = WF4; K = 1024; c0 = c - 16384; }
        else                { Wsrc = W5; dst = WF5; K = 2048; c0 = c - 49152; }
        const int t  = c0 >> 10;        // k-step
        const int r  = c0 & 1023;
        const int d  = r >> 2;
        const int lg = r & 3;
        const float* src = Wsrc + (size_t)d * K + t * 32 + lg * 8;
        f16x8 hv;
        #pragma unroll
        for (int j = 0; j < 8; ++j) hv[j] = (_Float16)src[j];
        *(f16x8*)(dst + (size_t)c0 * 8) = hv;
    } else if (bidx < 704) {
        const int k = bidx - 448;
        W1T[(size_t)k * 256 + tid] = W1[(size_t)tid * 256 + k];
    } else {
        const int k = bidx - 704;
        W2T[(size_t)k * 256 + tid] = W2[(size_t)tid * 256 + k];
    }
}

// ---- roi_setup2: per (n,s) compressed bilinear weight lists + pos-enc ------
__global__ __launch_bounds__(256)
void roi_setup2_kernel(const float* __restrict__ boxes,
                       const float* __restrict__ b3, const float* __restrict__ b4,
                       const float* __restrict__ b5,
                       const int* __restrict__ iw_p, const int* __restrict__ ih_p,
                       float* __restrict__ SREC, float* __restrict__ P)
{
    const int n   = blockIdx.x;
    const int s   = blockIdx.y;
    const int tid = threadIdx.x;

    int H, W;
    const float* bp;
    if (s == 0)      { H = 128; W = 128; bp = b3; }
    else if (s == 1) { H = 64;  W = 64;  bp = b4; }
    else             { H = 32;  W = 32;  bp = b5; }

    __shared__ float wy[32];
    __shared__ float wx[48];
    __shared__ int   sh_r0, sh_rs, sh_x0, sh_xs;
    __shared__ float sh_syc, sh_sxc;

    if (tid < 32)              wy[tid]      = 0.0f;
    if (tid >= 32 && tid < 80) wx[tid - 32] = 0.0f;
    __syncthreads();

    const float scale = fminf((float)W / ((float)(*iw_p) + 1e-6f),
                              (float)H / ((float)(*ih_p) + 1e-6f));
    float* rec = &SREC[(size_t)(n * 3 + s) * 64];

    if (tid == 0) {
        float c1 = boxes[(size_t)n * 4 + 1] * scale - 0.5f;
        float c2 = boxes[(size_t)n * 4 + 3] * scale - 0.5f;
        float bs = (c2 - c1) / 3.0f;
        int   yls[6], yhs[6], vv[6];
        float lys[6];
        int r0 = INT_MAX; float cnt = 0.0f;
        #pragma unroll
        for (int i = 0; i < 6; ++i) {
            float off = 0.25f + 0.5f * (float)i;
            float ys  = c1 + bs * off;
            int v = (ys >= -1.0f) && (ys <= (float)H);
            float yc = fmaxf(ys, 0.0f);
            int yl = (int)floorf(yc); if (yl > H - 1) yl = H - 1;
            int yh = yl + 1;          if (yh > H - 1) yh = H - 1;
            float ly = yc - (float)yl;
            yls[i] = yl; yhs[i] = yh; lys[i] = ly; vv[i] = v;
            if (v) { r0 = min(r0, yl); cnt += 1.0f; }
        }
        if (r0 == INT_MAX) r0 = 0;
        int rmax = 0;
        #pragma unroll
        for (int i = 0; i < 6; ++i) if (vv[i]) {
            int a = min(yls[i] - r0, 31);
            int h = min(yhs[i] - r0, 31);
            wy[a] += 1.0f - lys[i];
            wy[h] += lys[i];
            rmax = max(rmax, h);
        }
        sh_r0 = r0; sh_rs = rmax + 1; sh_syc = cnt;
        int cntn = 0;
        for (int r = 0; r <= rmax && cntn < 12; ++r) {
            if (wy[r] != 0.0f) {
                rec[4 + cntn]  = (float)(r0 + r);
                rec[16 + cntn] = wy[r];
                ++cntn;
            }
        }
        rec[0] = (float)cntn;
    }
    if (tid == 1) {
        float c1 = boxes[(size_t)n * 4 + 0] * scale - 0.5f;
        float c2 = boxes[(size_t)n * 4 + 2] * scale - 0.5f;
        float bs = (c2 - c1) / 3.0f;
        int   xls[6], xhs[6], vv[6];
        float lxs[6];
        int x0r = INT_MAX; float cnt = 0.0f;
        #pragma unroll
        for (int i = 0; i < 6; ++i) {
            float off = 0.25f + 0.5f * (float)i;
            float xs  = c1 + bs * off;
            int v = (xs >= -1.0f) && (xs <= (float)W);
            float xc = fmaxf(xs, 0.0f);
            int xl = (int)floorf(xc); if (xl > W - 1) xl = W - 1;
            int xh = xl + 1;          if (xh > W - 1) xh = W - 1;
            float lx = xc - (float)xl;
            xls[i] = xl; xhs[i] = xh; lxs[i] = lx; vv[i] = v;
            if (v) { x0r = min(x0r, xl); cnt += 1.0f; }
        }
        if (x0r == INT_MAX) x0r = 0;
        int imax = 0;
        #pragma unroll
        for (int i = 0; i < 6; ++i) if (vv[i]) {
            int a = min(xls[i] - x0r, 47);
            int h = min(xhs[i] - x0r, 47);
            wx[a] += 1.0f - lxs[i];
            wx[h] += lxs[i];
            imax = max(imax, h);
        }
        sh_x0 = x0r; sh_xs = imax + 1; sh_sxc = cnt;
        int cntn = 0;
        for (int j = 0; j <= imax && cntn < 12; ++j) {
            if (wx[j] != 0.0f) {
                rec[28 + cntn] = (float)(x0r + j);
                rec[40 + cntn] = wx[j];
                ++cntn;
            }
        }
        rec[1] = (float)cntn;
    }
    __syncthreads();

    const int r0 = sh_r0, rs = sh_rs, x0 = sh_x0, xsr = sh_xs;

    {
        const int d = tid;
        const float syc = sh_syc, sxc = sh_sxc;
        float val;
        if (d < 128) {
            int   t     = d >> 2;
            float invf  = expf(-(float)t * (logf(10000.0f) / 32.0f));
            float istep = 1.0f / (float)(H - 1);
            float sum = 0.0f;
            for (int r = 0; r < rs; ++r) {
                float w = wy[r];
                if (w != 0.0f) {
                    float ang = (float)(r0 + r) * istep * invf;
                    float sn, cs; sincosf(ang, &sn, &cs);
                    sum = fmaf(w, (d & 1) ? cs : sn, sum);
                }
            }
            val = sxc * sum;
        } else {
            int   d2    = d - 128;
            int   t     = d2 >> 2;
            float invf  = expf(-(float)t * (logf(10000.0f) / 32.0f));
            float istep = 1.0f / (float)(W - 1);
            float sum = 0.0f;
            for (int j = 0; j < xsr; ++j) {
                float w = wx[j];
                if (w != 0.0f) {
                    float ang = (float)(x0 + j) * istep * invf;
                    float sn, cs; sincosf(ang, &sn, &cs);
                    sum = fmaf(w, (d & 1) ? cs : sn, sum);
                }
            }
            val = syc * sum;
        }
        float cnt = syc * sxc;
        P[((size_t)n * 3 + s) * 256 + d] = (val + cnt * bp[d]) * (1.0f / 36.0f);
    }
}

// ---- proj6: dense fp16 MFMA projection, global_load_lds A-staging ----------
// Block = 8 waves (512 thr) = 64 px x 256 d. Wave = 32 px x 64 d
// (2 m-tiles x 4 n-tiles). BK = 32. A staged into LDS (double buffer, 8KB
// each) as px-major [8px][8k] 256B tiles: wave wv stages px-tile wv across
// the 4 k-tiles (one width-4 global_load_lds each). MFMA A-fragment = 2
// contiguous ds_read_b128. B in fragment-order registers, 2 steps ahead.
__global__ __launch_bounds__(512)
void proj6_kernel(const float* __restrict__ p3, const float* __restrict__ p4,
                  const float* __restrict__ p5,
                  const __half* __restrict__ WF3, const __half* __restrict__ WF4,
                  const __half* __restrict__ WF5,
                  __half* __restrict__ F3, __half* __restrict__ F4,
                  __half* __restrict__ F5,
                  int n5, int n4)
{
    const int bid = blockIdx.x;
    const float* feat; const __half* WF; __half* F;
    int C, HW, m0;
    if (bid < n5)           { C = 2048; HW = 1024;  feat = p5; WF = WF5; F = F5; m0 = bid * 64; }
    else if (bid < n5 + n4) { C = 1024; HW = 4096;  feat = p4; WF = WF4; F = F4; m0 = (bid - n5) * 64; }
    else                    { C = 512;  HW = 16384; feat = p3; WF = WF3; F = F3; m0 = (bid - n5 - n4) * 64; }

    const int tid = threadIdx.x;
    const int wv  = tid >> 6;           // 0..7
    const int l   = tid & 63;
    const int lm  = l & 15;
    const int lg  = l >> 4;             // k-group 0..3
    const int dq  = wv & 3;             // d-quarter (64 d)
    const int ph  = wv >> 2;            // px-half (32 px)
    const int b    = m0 / HW;
    const int pos0 = m0 % HW;
    const int nk   = C >> 5;            // 16/32/64 (always even)

    __shared__ float sa[2][2048];       // 2 x 8KB A-tiles

    // staging: lane l of wave wv covers px = wv*8 + (l>>3), k = i*8 + (l&7)
    const float* a_st = feat + (size_t)b * C * HW + pos0
                      + (size_t)(l & 7) * HW + (wv << 3) + (l >> 3);
    const size_t kstep_str = (size_t)32 * HW;   // elements per K-step
    const size_t ktile_str = (size_t)8 * HW;    // elements per k-tile

    // B: per-lane fragment base (verified formula from proj5)
    const __half* wbase = WF + ((size_t)(dq * 64 + lm) * 4 + lg) * 8;

    // A-fragment LDS read offsets (dwords), loop-invariant
    const int pxq0 = ph * 32 + lm;
    const int pxq1 = pxq0 + 16;
    const int ro0 = (((pxq0 >> 3) << 2) + lg) * 64 + ((pxq0 & 7) << 3);
    const int ro1 = (((pxq1 >> 3) << 2) + lg) * 64 + ((pxq1 & 7) << 3);

    f32x4 acc[8];
    #pragma unroll
    for (int i = 0; i < 8; ++i) acc[i] = (f32x4){0.f, 0.f, 0.f, 0.f};

    f16x8 bc[4], bn[4];

    // prologue: stage A[0], load B[0],B[1]
    {
        const float* s = a_st;
        float* d0 = &sa[0][(wv * 4) * 64];
        GLD4(s,                 d0);
        GLD4(s + ktile_str,     d0 + 64);
        GLD4(s + 2 * ktile_str, d0 + 128);
        GLD4(s + 3 * ktile_str, d0 + 192);
    }
    #pragma unroll
    for (int nt = 0; nt < 4; ++nt) bc[nt] = *(const f16x8*)(wbase + nt * 512);
    #pragma unroll
    for (int nt = 0; nt < 4; ++nt) bn[nt] = *(const f16x8*)(wbase + 8192 + nt * 512);
    __syncthreads();

    for (int t = 0; t < nk; t += 2) {
        // ---- even: consume sa[0]=A[t], bc=B[t]; stage A[t+1]->sa[1] ----
        {
            const float* s = a_st + (size_t)(t + 1) * kstep_str;   // t+1 < nk (nk even)
            float* d0 = &sa[1][(wv * 4) * 64];
            GLD4(s,                 d0);
            GLD4(s + ktile_str,     d0 + 64);
            GLD4(s + 2 * ktile_str, d0 + 128);
            GLD4(s + 3 * ktile_str, d0 + 192);

            const float* bufc = sa[0];
            const float4 va = *(const float4*)(bufc + ro0);
            const float4 vb = *(const float4*)(bufc + ro0 + 4);
            const float4 vc = *(const float4*)(bufc + ro1);
            const float4 vd = *(const float4*)(bufc + ro1 + 4);
            f16x8 af0, af1;
            af0[0] = (_Float16)va.x; af0[1] = (_Float16)va.y;
            af0[2] = (_Float16)va.z; af0[3] = (_Float16)va.w;
            af0[4] = (_Float16)vb.x; af0[5] = (_Float16)vb.y;
            af0[6] = (_Float16)vb.z; af0[7] = (_Float16)vb.w;
            af1[0] = (_Float16)vc.x; af1[1] = (_Float16)vc.y;
            af1[2] = (_Float16)vc.z; af1[3] = (_Float16)vc.w;
            af1[4] = (_Float16)vd.x; af1[5] = (_Float16)vd.y;
            af1[6] = (_Float16)vd.z; af1[7] = (_Float16)vd.w;
            #pragma unroll
            for (int nt = 0; nt < 4; ++nt) {
                acc[nt]     = __builtin_amdgcn_mfma_f32_16x16x32_f16(af0, bc[nt], acc[nt],     0, 0, 0);
                acc[nt + 4] = __builtin_amdgcn_mfma_f32_16x16x32_f16(af1, bc[nt], acc[nt + 4], 0, 0, 0);
            }
            if (t + 2 < nk) {
                const __half* wb = wbase + (size_t)(t + 2) * 8192;
                #pragma unroll
                for (int nt = 0; nt < 4; ++nt) bc[nt] = *(const f16x8*)(wb + nt * 512);
            }
            __syncthreads();
        }
        // ---- odd: consume sa[1]=A[t+1], bn=B[t+1]; stage A[t+2]->sa[0] ----
        {
            if (t + 2 < nk) {
                const float* s = a_st + (size_t)(t + 2) * kstep_str;
                float* d0 = &sa[0][(wv * 4) * 64];
                GLD4(s,                 d0);
                GLD4(s + ktile_str,     d0 + 64);
                GLD4(s + 2 * ktile_str, d0 + 128);
                GLD4(s + 3 * ktile_str, d0 + 192);
            }
            const float* bufc = sa[1];
            const float4 va = *(const float4*)(bufc + ro0);
            const float4 vb = *(const float4*)(bufc + ro0 + 4);
            const float4 vc = *(const float4*)(bufc + ro1);
            const float4 vd = *(const float4*)(bufc + ro1 + 4);
            f16x8 af0, af1;
            af0[0] = (_Float16)va.x; af0[1] = (_Float16)va.y;
            af0[2] = (_Float16)va.z; af0[3] = (_Float16)va.w;
            af0[4] = (_Float16)vb.x; af0[5] = (_Float16)vb.y;
            af0[6] = (_Float16)vb.z; af0[7] = (_Float16)vb.w;
            af1[0] = (_Float16)vc.x; af1[1] = (_Float16)vc.y;
            af1[2] = (_Float16)vc.z; af1[3] = (_Float16)vc.w;
            af1[4] = (_Float16)vd.x; af1[5] = (_Float16)vd.y;
            af1[6] = (_Float16)vd.z; af1[7] = (_Float16)vd.w;
            #pragma unroll
            for (int nt = 0; nt < 4; ++nt) {
                acc[nt]     = __builtin_amdgcn_mfma_f32_16x16x32_f16(af0, bn[nt], acc[nt],     0, 0, 0);
                acc[nt + 4] = __builtin_amdgcn_mfma_f32_16x16x32_f16(af1, bn[nt], acc[nt + 4], 0, 0, 0);
            }
            if (t + 3 < nk) {
                const __half* wb = wbase + (size_t)(t + 3) * 8192;
                #pragma unroll
                for (int nt = 0; nt < 4; ++nt) bn[nt] = *(const f16x8*)(wb + nt * 512);
            }
            __syncthreads();
        }
    }

    // store: d = dq*64 + nt*16 + lm (col=lane&15), px row = lg*4 + i
    #pragma unroll
    for (int mt = 0; mt < 2; ++mt) {
        #pragma unroll
        for (int nt = 0; nt < 4; ++nt) {
            #pragma unroll
            for (int i = 0; i < 4; ++i) {
                const int px = pos0 + ph * 32 + mt * 16 + lg * 4 + i;
                const int d  = dq * 64 + nt * 16 + lm;
                F[((size_t)b * HW + px) * 256 + d] = __float2half(acc[nt + mt * 4][i]);
            }
        }
    }
}

// ---- sample2: per (n,s) channel-last bilinear sampling ---------------------
__global__ __launch_bounds__(256)
void sample2_kernel(const __half* __restrict__ F3, const __half* __restrict__ F4,
                    const __half* __restrict__ F5,
                    const float* __restrict__ SREC, const float* __restrict__ P,
                    float* __restrict__ tokp, int K100)
{
    const int n = blockIdx.x;
    const int s = blockIdx.y;
    const int d = threadIdx.x;
    const int b = n / K100;

    __shared__ float rsh[64];
    if (d < 64) rsh[d] = SREC[(size_t)(n * 3 + s) * 64 + d];
    __syncthreads();

    const __half* F; int HW, W;
    if (s == 0)      { F = F3; HW = 16384; W = 128; }
    else if (s == 1) { F = F4; HW = 4096;  W = 64; }
    else             { F = F5; HW = 1024;  W = 32; }

    const int ny = (int)rsh[0];
    const int nx = (int)rsh[1];
    const size_t base = (size_t)b * HW * 256 + d;

    float acc = 0.0f;
    for (int i = 0; i < ny; ++i) {
        const int   row = (int)rsh[4 + i];
        const float wyv = rsh[16 + i];
        const size_t rb = base + (size_t)(row * W) * 256;
        float rsum = 0.0f;
        for (int j = 0; j < nx; ++j) {
            const int   col = (int)rsh[28 + j];
            const float wxv = rsh[40 + j];
            rsum = fmaf(wxv, __half2float(F[rb + (size_t)col * 256]), rsum);
        }
        acc = fmaf(wyv, rsum, acc);
    }
    tokp[(size_t)(n * 3 + s) * 256 + d] = acc * (1.0f / 36.0f)
                                        + P[(size_t)(n * 3 + s) * 256 + d];
}

// ---- mlp2: sum 3 partials, LayerNorm, Linear-GELU-Linear -------------------
__global__ __launch_bounds__(256)
void mlp2_kernel(const float* __restrict__ tokp,
                 const float* __restrict__ lng, const float* __restrict__ lnb,
                 const float* __restrict__ W1T, const float* __restrict__ b1,
                 const float* __restrict__ W2T, const float* __restrict__ b2,
                 float* __restrict__ out, int N)
{
    const int n0  = blockIdx.x * 8;
    const int tid = threadIdx.x;

    __shared__ float tokl[8][257];
    __shared__ float hl[8][257];
    __shared__ float mval[8], rstd[8];

    #pragma unroll
    for (int t = 0; t < 8; ++t) {
        const size_t nb = (size_t)(n0 + t) * 3 * 256 + tid;
        tokl[t][tid] = tokp[nb] + tokp[nb + 256] + tokp[nb + 512];
    }
    __syncthreads();

    const int wv = tid >> 6, lane = tid & 63;
    for (int t = wv; t < 8; t += 4) {
        float x0 = tokl[t][lane], x1 = tokl[t][lane + 64];
        float x2 = tokl[t][lane + 128], x3 = tokl[t][lane + 192];
        float sm = x0 + x1 + x2 + x3;
        float sq = x0 * x0 + x1 * x1 + x2 * x2 + x3 * x3;
        #pragma unroll
        for (int o = 32; o; o >>= 1) { sm += __shfl_xor(sm, o); sq += __shfl_xor(sq, o); }
        if (lane == 0) {
            float m   = sm * (1.0f / 256.0f);
            float var = sq * (1.0f / 256.0f) - m * m;
            mval[t] = m;
            rstd[t] = rsqrtf(var + 1e-5f);
        }
    }
    __syncthreads();

    const float g = lng[tid], be = lnb[tid];
    #pragma unroll
    for (int t = 0; t < 8; ++t)
        hl[t][tid] = (tokl[t][tid] - mval[t]) * rstd[t] * g + be;
    __syncthreads();

    float acc[8];
    const float bb1 = b1[tid];
    #pragma unroll
    for (int t = 0; t < 8; ++t) acc[t] = bb1;
    for (int k = 0; k < 256; ++k) {
        float w = W1T[(size_t)k * 256 + tid];
        #pragma unroll
        for (int t = 0; t < 8; ++t) acc[t] = fmaf(hl[t][k], w, acc[t]);
    }
    __syncthreads();
    #pragma unroll
    for (int t = 0; t < 8; ++t) tokl[t][tid] = gelu_exact(acc[t]);
    __syncthreads();

    const float bb2 = b2[tid];
    #pragma unroll
    for (int t = 0; t < 8; ++t) acc[t] = bb2;
    for (int k = 0; k < 256; ++k) {
        float w = W2T[(size_t)k * 256 + tid];
        #pragma unroll
        for (int t = 0; t < 8; ++t) acc[t] = fmaf(tokl[t][k], w, acc[t]);
    }
    #pragma unroll
    for (int t = 0; t < 8; ++t)
        out[(size_t)(n0 + t) * 256 + tid] = acc[t];
}

// ======================= OLD (fallback) PIPELINE ============================

__global__ __launch_bounds__(256)
void build_wt_kernel(const float* __restrict__ W3, const float* __restrict__ W4,
                     const float* __restrict__ W5, const float* __restrict__ W1,
                     const float* __restrict__ W2,
                     float* __restrict__ WT, float* __restrict__ W1T,
                     float* __restrict__ W2T)
{
    int k = blockIdx.x;
    int d = threadIdx.x;
    if (k < 512)       WT[(size_t)k * 256 + d]          = W3[(size_t)d * 512  + k];
    else if (k < 1536) WT[(size_t)k * 256 + d]          = W4[(size_t)d * 1024 + (k - 512)];
    else if (k < 3584) WT[(size_t)k * 256 + d]          = W5[(size_t)d * 2048 + (k - 1536)];
    else if (k < 3840) W1T[(size_t)(k - 3584) * 256 + d] = W1[(size_t)d * 256 + (k - 3584)];
    else               W2T[(size_t)(k - 3840) * 256 + d] = W2[(size_t)d * 256 + (k - 3840)];
}

__global__ __launch_bounds__(256)
void roi_setup_kernel(const float* __restrict__ boxes,
                      const float* __restrict__ b3, const float* __restrict__ b4,
                      const float* __restrict__ b5,
                      const int* __restrict__ iw_p, const int* __restrict__ ih_p,
                      float* __restrict__ WREC, float* __restrict__ P)
{
    const int n   = blockIdx.x;
    const int s   = blockIdx.y;
    const int tid = threadIdx.x;

    int H, W;
    const float* bp;
    if (s == 0)      { H = 128; W = 128; bp = b3; }
    else if (s == 1) { H = 64;  W = 64;  bp = b4; }
    else             { H = 32;  W = 32;  bp = b5; }

    __shared__ float wy[32];
    __shared__ float wx[48];
    __shared__ int   sh_r0, sh_rs, sh_x0, sh_nc;
    __shared__ float sh_syc, sh_sxc;

    if (tid < 32)                 wy[tid]      = 0.0f;
    if (tid >= 32 && tid < 80)    wx[tid - 32] = 0.0f;
    __syncthreads();

    const float scale = fminf((float)W / ((float)(*iw_p) + 1e-6f),
                              (float)H / ((float)(*ih_p) + 1e-6f));

    if (tid == 0) {
        float c1 = boxes[(size_t)n * 4 + 1] * scale - 0.5f;
        float c2 = boxes[(size_t)n * 4 + 3] * scale - 0.5f;
        float bs = (c2 - c1) / 3.0f;
        int   yls[6], yhs[6], vv[6];
        float lys[6];
        int r0 = INT_MAX; float cnt = 0.0f;
        #pragma unroll
        for (int i = 0; i < 6; ++i) {
            float off = 0.25f + 0.5f * (float)i;
            float ys  = c1 + bs * off;
            int v = (ys >= -1.0f) && (ys <= (float)H);
            float yc = fmaxf(ys, 0.0f);
            int yl = (int)floorf(yc); if (yl > H - 1) yl = H - 1;
            int yh = yl + 1;          if (yh > H - 1) yh = H - 1;
            float ly = yc - (float)yl;
            yls[i] = yl; yhs[i] = yh; lys[i] = ly; vv[i] = v;
            if (v) { r0 = min(r0, yl); cnt += 1.0f; }
        }
        if (r0 == INT_MAX) r0 = 0;
        int rmax = 0;
        #pragma unroll
        for (int i = 0; i < 6; ++i) if (vv[i]) {
            int a = min(yls[i] - r0, 31);
            int h = min(yhs[i] - r0, 31);
            wy[a] += 1.0f - lys[i];
            wy[h] += lys[i];
            rmax = max(rmax, h);
        }
        sh_r0 = r0; sh_rs = rmax + 1; sh_syc = cnt;
    }
    if (tid == 1) {
        float c1 = boxes[(size_t)n * 4 + 0] * scale - 0.5f;
        float c2 = boxes[(size_t)n * 4 + 2] * scale - 0.5f;
        float bs = (c2 - c1) / 3.0f;
        int   xls[6], xhs[6], vv[6];
        float lxs[6];
        int x0r = INT_MAX; float cnt = 0.0f;
        #pragma unroll
        for (int i = 0; i < 6; ++i) {
            float off = 0.25f + 0.5f * (float)i;
            float xs  = c1 + bs * off;
            int v = (xs >= -1.0f) && (xs <= (float)W);
            float xc = fmaxf(xs, 0.0f);
            int xl = (int)floorf(xc); if (xl > W - 1) xl = W - 1;
            int xh = xl + 1;          if (xh > W - 1) xh = W - 1;
            float lx = xc - (float)xl;
            xls[i] = xl; xhs[i] = xh; lxs[i] = lx; vv[i] = v;
            if (v) { x0r = min(x0r, xl); cnt += 1.0f; }
        }
        if (x0r == INT_MAX) x0r = 0;
        int x0 = x0r & ~15;
        int imax = 0;
        #pragma unroll
        for (int i = 0; i < 6; ++i) if (vv[i]) {
            int a = min(xls[i] - x0, 47);
            int h = min(xhs[i] - x0, 47);
            wx[a] += 1.0f - lxs[i];
            wx[h] += lxs[i];
            imax = max(imax, h);
        }
        int nc = imax / 16 + 1;
        int ncmax = (W - x0) >> 4;
        nc = min(nc, ncmax);
        sh_x0 = x0; sh_nc = max(nc, 1); sh_sxc = cnt;
    }
    __syncthreads();

    const int r0 = sh_r0, rs = sh_rs, x0 = sh_x0, nc = sh_nc;

    float* rec = &WREC[(size_t)(n * 3 + s) * 96];
    if (tid < 32)                 rec[tid]      = wy[tid];
    else if (tid < 80)            rec[tid]      = wx[tid - 32];
    else if (tid == 80)           rec[80]       = (float)r0;
    else if (tid == 81)           rec[81]       = (float)rs;
    else if (tid == 82)           rec[82]       = (float)x0;
    else if (tid == 83)           rec[83]       = (float)nc;
    else if (tid == 84)           rec[84]       = sh_syc;
    else if (tid == 85)           rec[85]       = sh_sxc;

    {
        const int d = tid;
        const float syc = sh_syc, sxc = sh_sxc;
        float val;
        if (d < 128) {
            int   t     = d >> 2;
            float invf  = expf(-(float)t * (logf(10000.0f) / 32.0f));
            float istep = 1.0f / (float)(H - 1);
            float sum = 0.0f;
            for (int r = 0; r < rs; ++r) {
                float w = wy[r];
                float ang = (float)(r0 + r) * istep * invf;
                float sn, cs; sincosf(ang, &sn, &cs);
                sum = fmaf(w, (d & 1) ? cs : sn, sum);
            }
            val = sxc * sum;
        } else {
            int   d2    = d - 128;
            int   t     = d2 >> 2;
            float invf  = expf(-(float)t * (logf(10000.0f) / 32.0f));
            float istep = 1.0f / (float)(W - 1);
            float sum = 0.0f;
            int nx = nc << 4;
            for (int j = 0; j < nx; ++j) {
                float w = wx[j];
                if (w != 0.0f) {
                    float ang = (float)(x0 + j) * istep * invf;
                    float sn, cs; sincosf(ang, &sn, &cs);
                    sum = fmaf(w, (d & 1) ? cs : sn, sum);
                }
            }
            val = syc * sum;
        }
        float cnt = syc * sxc;
        P[((size_t)n * 3 + s) * 256 + d] = (val + cnt * bp[d]) * (1.0f / 36.0f);
    }
}

__global__ __launch_bounds__(256)
void roi_gather_kernel(const float* __restrict__ p3, const float* __restrict__ p4,
                       const float* __restrict__ p5,
                       const float* __restrict__ WREC,
                       float* __restrict__ G, int K)
{
    const int yc  = blockIdx.x;
    const int n   = blockIdx.y;
    const int tid = threadIdx.x;

    int s, chunk;
    if (yc < 8)       { s = 0; chunk = yc; }
    else if (yc < 24) { s = 1; chunk = yc - 8; }
    else              { s = 2; chunk = yc - 24; }

    int C, H, W, koff;
    const float* feat;
    if (s == 0)      { C = 512;  H = 128; W = 128; koff = 0;    feat = p3; }
    else if (s == 1) { C = 1024; H = 64;  W = 64;  koff = 512;  feat = p4; }
    else             { C = 2048; H = 32;  W = 32;  koff = 1536; feat = p5; }
    const int HW = H * W;
    const int b  = n / K;

    __shared__ float sh[96];
    if (tid < 96) sh[tid] = WREC[(size_t)(n * 3 + s) * 96 + tid];
    __syncthreads();

    const int r0 = (int)sh[80];
    const int rs = (int)sh[81];
    const int x0 = (int)sh[82];
    const int nc = (int)sh[83];

    const int c    = chunk * 64 + (tid >> 2);
    const int slot = tid & 3;

    const float* fp = feat + (size_t)b * C * HW + (size_t)c * HW
                    + (size_t)r0 * W + x0 + slot * 4;

    float acc = 0.0f;
    for (int ch = 0; ch < nc; ++ch) {
        const float4 wxv = *(const float4*)&sh[32 + (ch << 4) + slot * 4];
        const float* a = fp + (ch << 4);
        float4 ra = make_float4(0.f, 0.f, 0.f, 0.f);
        int r = 0;
        for (; r + 4 <= rs; r += 4) {
            const float4 v0 = *(const float4*)(a + (size_t)(r + 0) * W);
            const float4 v1 = *(const float4*)(a + (size_t)(r + 1) * W);
            const float4 v2 = *(const float4*)(a + (size_t)(r + 2) * W);
            const float4 v3 = *(const float4*)(a + (size_t)(r + 3) * W);
            const float w0 = sh[r], w1 = sh[r + 1], w2 = sh[r + 2], w3 = sh[r + 3];
            ra.x = fmaf(w0, v0.x, ra.x); ra.y = fmaf(w0, v0.y, ra.y);
            ra.z = fmaf(w0, v0.z, ra.z); ra.w = fmaf(w0, v0.w, ra.w);
            ra.x = fmaf(w1, v1.x, ra.x); ra.y = fmaf(w1, v1.y, ra.y);
            ra.z = fmaf(w1, v1.z, ra.z); ra.w = fmaf(w1, v1.w, ra.w);
            ra.x = fmaf(w2, v2.x, ra.x); ra.y = fmaf(w2, v2.y, ra.y);
            ra.z = fmaf(w2, v2.z, ra.z); ra.w = fmaf(w2, v2.w, ra.w);
            ra.x = fmaf(w3, v3.x, ra.x); ra.y = fmaf(w3, v3.y, ra.y);
            ra.z = fmaf(w3, v3.z, ra.z); ra.w = fmaf(w3, v3.w, ra.w);
        }
        for (; r < rs; ++r) {
            const float4 v = *(const float4*)(a + (size_t)r * W);
            const float w = sh[r];
            ra.x = fmaf(w, v.x, ra.x); ra.y = fmaf(w, v.y, ra.y);
            ra.z = fmaf(w, v.z, ra.z); ra.w = fmaf(w, v.w, ra.w);
        }
        float dsum = ra.x * wxv.x + ra.y * wxv.y + ra.z * wxv.z + ra.w * wxv.w;
        acc += dsum;
    }
    acc += __shfl_xor(acc, 1, 4);
    acc += __shfl_xor(acc, 2, 4);
    if (slot == 0)
        G[(size_t)n * 3584 + koff + c] = acc * (1.0f / 36.0f);
}

__global__ __launch_bounds__(256)
void proj_gemm_kernel(const float* __restrict__ G, const float* __restrict__ WT,
                      float* __restrict__ part, int N)
{
    const int n0  = blockIdx.x * 8;
    const int kc  = blockIdx.y;
    const int tid = threadIdx.x;

    __shared__ float gl[8][128];
    float acc[8];
    #pragma unroll
    for (int t = 0; t < 8; ++t) acc[t] = 0.0f;

    const int kbase = kc * 512;
    const int lt  = tid >> 5;
    const int lc  = (tid & 31) * 4;

    for (int sub = 0; sub < 4; ++sub) {
        const float4 g4 = *(const float4*)&G[(size_t)(n0 + lt) * 3584 + kbase + sub * 128 + lc];
        *(float4*)&gl[lt][lc] = g4;
        __syncthreads();
        const float* wtp = &WT[(size_t)(kbase + sub * 128) * 256 + tid];
        #pragma unroll 4
        for (int k = 0; k < 128; ++k) {
            float w = wtp[(size_t)k * 256];
            #pragma unroll
            for (int t = 0; t < 8; ++t) acc[t] = fmaf(gl[t][k], w, acc[t]);
        }
        __syncthreads();
    }
    #pragma unroll
    for (int t = 0; t < 8; ++t)
        part[((size_t)kc * N + n0 + t) * 256 + tid] = acc[t];
}

__global__ __launch_bounds__(256)
void mlp_kernel(const float* __restrict__ part, const float* __restrict__ P,
                const float* __restrict__ lng, const float* __restrict__ lnb,
                const float* __restrict__ W1T, const float* __restrict__ b1,
                const float* __restrict__ W2T, const float* __restrict__ b2,
                float* __restrict__ out, int N)
{
    const int n0  = blockIdx.x * 8;
    const int tid = threadIdx.x;

    __shared__ float tokl[8][257];
    __shared__ float hl[8][257];
    __shared__ float mval[8], rstd[8];

    #pragma unroll
    for (int t = 0; t < 8; ++t) {
        const int n = n0 + t;
        float v = 0.0f;
        #pragma unroll
        for (int c = 0; c < 7; ++c) v += part[((size_t)c * N + n) * 256 + tid];
        #pragma unroll
        for (int s = 0; s < 3; ++s) v += P[((size_t)n * 3 + s) * 256 + tid];
        tokl[t][tid] = v;
    }
    __syncthreads();

    const int wv = tid >> 6, lane = tid & 63;
    for (int t = wv; t < 8; t += 4) {
        float x0 = tokl[t][lane], x1 = tokl[t][lane + 64];
        float x2 = tokl[t][lane + 128], x3 = tokl[t][lane + 192];
        float sm = x0 + x1 + x2 + x3;
        float sq = x0 * x0 + x1 * x1 + x2 * x2 + x3 * x3;
        #pragma unroll
        for (int o = 32; o; o >>= 1) { sm += __shfl_xor(sm, o); sq += __shfl_xor(sq, o); }
        if (lane == 0) {
            float m   = sm * (1.0f / 256.0f);
            float var = sq * (1.0f / 256.0f) - m * m;
            mval[t] = m;
            rstd[t] = rsqrtf(var + 1e-5f);
        }
    }
    __syncthreads();

    const float g = lng[tid], be = lnb[tid];
    #pragma unroll
    for (int t = 0; t < 8; ++t)
        hl[t][tid] = (tokl[t][tid] - mval[t]) * rstd[t] * g + be;
    __syncthreads();

    float acc[8];
    const float bb1 = b1[tid];
    #pragma unroll
    for (int t = 0; t < 8; ++t) acc[t] = bb1;
    for (int k = 0; k < 256; ++k) {
        float w = W1T[(size_t)k * 256 + tid];
        #pragma unroll
        for (int t = 0; t < 8; ++t) acc[t] = fmaf(hl[t][k], w, acc[t]);
    }
    __syncthreads();
    #pragma unroll
    for (int t = 0; t < 8; ++t) tokl[t][tid] = gelu_exact(acc[t]);
    __syncthreads();

    const float bb2 = b2[tid];
    #pragma unroll
    for (int t = 0; t < 8; ++t) acc[t] = bb2;
    for (int k = 0; k < 256; ++k) {
        float w = W2T[(size_t)k * 256 + tid];
        #pragma unroll
        for (int t = 0; t < 8; ++t) acc[t] = fmaf(tokl[t][k], w, acc[t]);
    }
    #pragma unroll
    for (int t = 0; t < 8; ++t)
        out[(size_t)(n0 + t) * 256 + tid] = acc[t];
}

// ---------------------------------------------------------------------------
extern "C" void kernel_launch(void* const* d_in, const int* in_sizes, int n_in,
                              void* d_out, int out_size, void* d_ws, size_t ws_size,
                              hipStream_t stream)
{
    const float* p3    = (const float*)d_in[0];
    const float* p4    = (const float*)d_in[1];
    const float* p5    = (const float*)d_in[2];
    const float* boxes = (const float*)d_in[3];
    const float* W3    = (const float*)d_in[4];
    const float* b3    = (const float*)d_in[5];
    const float* W4    = (const float*)d_in[6];
    const float* b4    = (const float*)d_in[7];
    const float* W5    = (const float*)d_in[8];
    const float* b5    = (const float*)d_in[9];
    const float* lng   = (const float*)d_in[10];
    const float* lnb   = (const float*)d_in[11];
    const float* W1    = (const float*)d_in[12];
    const float* b1    = (const float*)d_in[13];
    const float* W2    = (const float*)d_in[14];
    const float* b2    = (const float*)d_in[15];
    const int*   iw    = (const int*)d_in[16];
    const int*   ih    = (const int*)d_in[17];

    const int B = in_sizes[0] / (512 * 128 * 128);   // 8
    const int N = out_size / 256;                    // 800
    const int K100 = N / B;                          // 100

    float* out = (float*)d_out;

    // ---- new-path workspace layout (bytes) ----
    const size_t szF3   = (size_t)B * 16384 * 256 * 2;
    const size_t szF4   = (size_t)B * 4096  * 256 * 2;
    const size_t szF5   = (size_t)B * 1024  * 256 * 2;
    const size_t szWF   = (size_t)3584 * 256 * 2;
    const size_t szSREC = (size_t)N * 3 * 64 * 4;
    const size_t szP    = (size_t)N * 3 * 256 * 4;
    const size_t szTok  = (size_t)N * 3 * 256 * 4;
    const size_t szWT12 = (size_t)256 * 256 * 4;
    const size_t need_new = szF3 + szF4 + szF5 + szWF + szSREC + szP + szTok + 2 * szWT12;

    if (ws_size >= need_new) {
        char* w = (char*)d_ws;
        __half* F3   = (__half*)w;            w += szF3;
        __half* F4   = (__half*)w;            w += szF4;
        __half* F5   = (__half*)w;            w += szF5;
        __half* WF   = (__half*)w;            w += szWF;
        float*  SREC = (float*)w;             w += szSREC;
        float*  P    = (float*)w;             w += szP;
        float*  tokp = (float*)w;             w += szTok;
        float*  W1T  = (float*)w;             w += szWT12;
        float*  W2T  = (float*)w;             w += szWT12;

        __half* WF3 = WF;                     // 512*256  halves (frag order)
        __half* WF4 = WF + 131072;            // 1024*256
        __half* WF5 = WF + 393216;            // 2048*256

        const int n5 = B * 1024  / 64;        // 128
        const int n4 = B * 4096  / 64;        // 512
        const int n3 = B * 16384 / 64;        // 2048

        build_wt3_kernel<<<960, 256, 0, stream>>>(W3, W4, W5, W1, W2,
                                                  WF3, WF4, WF5, W1T, W2T);
        roi_setup2_kernel<<<dim3(N, 3), 256, 0, stream>>>(boxes, b3, b4, b5, iw, ih, SREC, P);
        proj6_kernel<<<n5 + n4 + n3, 512, 0, stream>>>(p3, p4, p5, WF3, WF4, WF5,
                                                       F3, F4, F5, n5, n4);
        sample2_kernel<<<dim3(N, 3), 256, 0, stream>>>(F3, F4, F5, SREC, P, tokp, K100);
        mlp2_kernel<<<N / 8, 256, 0, stream>>>(tokp, lng, lnb, W1T, b1, W2T, b2, out, N);
    } else {
        // fallback: round-3 pipeline (~22 MB workspace)
        float* G    = (float*)d_ws;
        float* P    = G + (size_t)N * 3584;
        float* WT   = P + (size_t)N * 3 * 256;
        float* W1T  = WT + (size_t)3584 * 256;
        float* W2T  = W1T + (size_t)256 * 256;
        float* part = W2T + (size_t)256 * 256;
        float* WREC = part + (size_t)7 * N * 256;

        build_wt_kernel<<<4096, 256, 0, stream>>>(W3, W4, W5, W1, W2, WT, W1T, W2T);
        roi_setup_kernel<<<dim3(N, 3), 256, 0, stream>>>(boxes, b3, b4, b5, iw, ih, WREC, P);
        roi_gather_kernel<<<dim3(56, N), 256, 0, stream>>>(p3, p4, p5, WREC, G, K100);
        proj_gemm_kernel<<<dim3(N / 8, 7), 256, 0, stream>>>(G, WT, part, N);
        mlp_kernel<<<N / 8, 256, 0, stream>>>(part, P, lng, lnb, W1T, b1, W2T, b2, out, N);
    }
}

// Round 11
// 331.414 us; speedup vs baseline: 1.0300x; 1.0300x over previous
//
#include <hip/hip_runtime.h>
#include <hip/hip_fp16.h>
#include <math.h>

#ifndef INT_MAX
#define INT_MAX 0x7fffffff
#endif

typedef __attribute__((ext_vector_type(8))) _Float16 f16x8;
typedef __attribute__((ext_vector_type(4))) float   f32x4;

// ---------------------------------------------------------------------------
// Round 9 -> 10: proj6's dominant cost was LDS bank conflicts (7.16e7 ~= 116us:
// read start-banks only {0,8,16,24}). proj7: (1) pad LDS row stride 64->68
// dwords -> start banks uniform over all 8 slots -> ~0 conflicts; (2) BK=64
// (2 MFMA sub-steps per staged tile) -> half the barriers, 2x compute per
// vmcnt drain. Same verified indexing/store as proj5/proj6.
// ---------------------------------------------------------------------------

#define GLD4(src, dst)                                                        \
    __builtin_amdgcn_global_load_lds(                                         \
        (const __attribute__((address_space(1))) unsigned int*)(const void*)(src), \
        (__attribute__((address_space(3))) unsigned int*)(void*)(dst), 4, 0, 0)

__device__ __forceinline__ float gelu_exact(float x) {
    return 0.5f * x * (1.0f + erff(x * 0.70710678118654752f));
}

// ---- build_wt3: W3/4/5 -> fp16 fragment-order WF; transpose W1/W2 ----------
// WF layout (halves): WF[((t*256 + d)*4 + lg)*8 + j] = W[d][t*32 + lg*8 + j]
__global__ __launch_bounds__(256)
void build_wt3_kernel(const float* __restrict__ W3, const float* __restrict__ W4,
                      const float* __restrict__ W5, const float* __restrict__ W1,
                      const float* __restrict__ W2,
                      __half* __restrict__ WF3, __half* __restrict__ WF4,
                      __half* __restrict__ WF5,
                      float* __restrict__ W1T, float* __restrict__ W2T)
{
    const int bidx = blockIdx.x;
    const int tid  = threadIdx.x;
    if (bidx < 448) {
        const int c = bidx * 256 + tid;
        const float* Wsrc; __half* dst; int K, c0;
        if (c < 16384)      { Wsrc = W3; dst = WF3; K = 512;  c0 = c; }
        else if (c < 49152) { Wsrc = W4; dst = WF4; K = 1024; c0 = c - 16384; }
        else                { Wsrc = W5; dst = WF5; K = 2048; c0 = c - 49152; }
        const int t  = c0 >> 10;        // 32-k sub-step
        const int r  = c0 & 1023;
        const int d  = r >> 2;
        const int lg = r & 3;
        const float* src = Wsrc + (size_t)d * K + t * 32 + lg * 8;
        f16x8 hv;
        #pragma unroll
        for (int j = 0; j < 8; ++j) hv[j] = (_Float16)src[j];
        *(f16x8*)(dst + (size_t)c0 * 8) = hv;
    } else if (bidx < 704) {
        const int k = bidx - 448;
        W1T[(size_t)k * 256 + tid] = W1[(size_t)tid * 256 + k];
    } else {
        const int k = bidx - 704;
        W2T[(size_t)k * 256 + tid] = W2[(size_t)tid * 256 + k];
    }
}

// ---- roi_setup2: per (n,s) compressed bilinear weight lists + pos-enc ------
__global__ __launch_bounds__(256)
void roi_setup2_kernel(const float* __restrict__ boxes,
                       const float* __restrict__ b3, const float* __restrict__ b4,
                       const float* __restrict__ b5,
                       const int* __restrict__ iw_p, const int* __restrict__ ih_p,
                       float* __restrict__ SREC, float* __restrict__ P)
{
    const int n   = blockIdx.x;
    const int s   = blockIdx.y;
    const int tid = threadIdx.x;

    int H, W;
    const float* bp;
    if (s == 0)      { H = 128; W = 128; bp = b3; }
    else if (s == 1) { H = 64;  W = 64;  bp = b4; }
    else             { H = 32;  W = 32;  bp = b5; }

    __shared__ float wy[32];
    __shared__ float wx[48];
    __shared__ int   sh_r0, sh_rs, sh_x0, sh_xs;
    __shared__ float sh_syc, sh_sxc;

    if (tid < 32)              wy[tid]      = 0.0f;
    if (tid >= 32 && tid < 80) wx[tid - 32] = 0.0f;
    __syncthreads();

    const float scale = fminf((float)W / ((float)(*iw_p) + 1e-6f),
                              (float)H / ((float)(*ih_p) + 1e-6f));
    float* rec = &SREC[(size_t)(n * 3 + s) * 64];

    if (tid == 0) {
        float c1 = boxes[(size_t)n * 4 + 1] * scale - 0.5f;
        float c2 = boxes[(size_t)n * 4 + 3] * scale - 0.5f;
        float bs = (c2 - c1) / 3.0f;
        int   yls[6], yhs[6], vv[6];
        float lys[6];
        int r0 = INT_MAX; float cnt = 0.0f;
        #pragma unroll
        for (int i = 0; i < 6; ++i) {
            float off = 0.25f + 0.5f * (float)i;
            float ys  = c1 + bs * off;
            int v = (ys >= -1.0f) && (ys <= (float)H);
            float yc = fmaxf(ys, 0.0f);
            int yl = (int)floorf(yc); if (yl > H - 1) yl = H - 1;
            int yh = yl + 1;          if (yh > H - 1) yh = H - 1;
            float ly = yc - (float)yl;
            yls[i] = yl; yhs[i] = yh; lys[i] = ly; vv[i] = v;
            if (v) { r0 = min(r0, yl); cnt += 1.0f; }
        }
        if (r0 == INT_MAX) r0 = 0;
        int rmax = 0;
        #pragma unroll
        for (int i = 0; i < 6; ++i) if (vv[i]) {
            int a = min(yls[i] - r0, 31);
            int h = min(yhs[i] - r0, 31);
            wy[a] += 1.0f - lys[i];
            wy[h] += lys[i];
            rmax = max(rmax, h);
        }
        sh_r0 = r0; sh_rs = rmax + 1; sh_syc = cnt;
        int cntn = 0;
        for (int r = 0; r <= rmax && cntn < 12; ++r) {
            if (wy[r] != 0.0f) {
                rec[4 + cntn]  = (float)(r0 + r);
                rec[16 + cntn] = wy[r];
                ++cntn;
            }
        }
        rec[0] = (float)cntn;
    }
    if (tid == 1) {
        float c1 = boxes[(size_t)n * 4 + 0] * scale - 0.5f;
        float c2 = boxes[(size_t)n * 4 + 2] * scale - 0.5f;
        float bs = (c2 - c1) / 3.0f;
        int   xls[6], xhs[6], vv[6];
        float lxs[6];
        int x0r = INT_MAX; float cnt = 0.0f;
        #pragma unroll
        for (int i = 0; i < 6; ++i) {
            float off = 0.25f + 0.5f * (float)i;
            float xs  = c1 + bs * off;
            int v = (xs >= -1.0f) && (xs <= (float)W);
            float xc = fmaxf(xs, 0.0f);
            int xl = (int)floorf(xc); if (xl > W - 1) xl = W - 1;
            int xh = xl + 1;          if (xh > W - 1) xh = W - 1;
            float lx = xc - (float)xl;
            xls[i] = xl; xhs[i] = xh; lxs[i] = lx; vv[i] = v;
            if (v) { x0r = min(x0r, xl); cnt += 1.0f; }
        }
        if (x0r == INT_MAX) x0r = 0;
        int imax = 0;
        #pragma unroll
        for (int i = 0; i < 6; ++i) if (vv[i]) {
            int a = min(xls[i] - x0r, 47);
            int h = min(xhs[i] - x0r, 47);
            wx[a] += 1.0f - lxs[i];
            wx[h] += lxs[i];
            imax = max(imax, h);
        }
        sh_x0 = x0r; sh_xs = imax + 1; sh_sxc = cnt;
        int cntn = 0;
        for (int j = 0; j <= imax && cntn < 12; ++j) {
            if (wx[j] != 0.0f) {
                rec[28 + cntn] = (float)(x0r + j);
                rec[40 + cntn] = wx[j];
                ++cntn;
            }
        }
        rec[1] = (float)cntn;
    }
    __syncthreads();

    const int r0 = sh_r0, rs = sh_rs, x0 = sh_x0, xsr = sh_xs;

    {
        const int d = tid;
        const float syc = sh_syc, sxc = sh_sxc;
        float val;
        if (d < 128) {
            int   t     = d >> 2;
            float invf  = expf(-(float)t * (logf(10000.0f) / 32.0f));
            float istep = 1.0f / (float)(H - 1);
            float sum = 0.0f;
            for (int r = 0; r < rs; ++r) {
                float w = wy[r];
                if (w != 0.0f) {
                    float ang = (float)(r0 + r) * istep * invf;
                    float sn, cs; sincosf(ang, &sn, &cs);
                    sum = fmaf(w, (d & 1) ? cs : sn, sum);
                }
            }
            val = sxc * sum;
        } else {
            int   d2    = d - 128;
            int   t     = d2 >> 2;
            float invf  = expf(-(float)t * (logf(10000.0f) / 32.0f));
            float istep = 1.0f / (float)(W - 1);
            float sum = 0.0f;
            for (int j = 0; j < xsr; ++j) {
                float w = wx[j];
                if (w != 0.0f) {
                    float ang = (float)(x0 + j) * istep * invf;
                    float sn, cs; sincosf(ang, &sn, &cs);
                    sum = fmaf(w, (d & 1) ? cs : sn, sum);
                }
            }
            val = syc * sum;
        }
        float cnt = syc * sxc;
        P[((size_t)n * 3 + s) * 256 + d] = (val + cnt * bp[d]) * (1.0f / 36.0f);
    }
}

// ---- proj7: dense fp16 MFMA projection, padded-LDS staging, BK=64 ----------
// Block = 8 waves (512 thr) = 64 px x 256 d. Wave = 32 px x 64 d. Per K-step
// (64 k): stage 16KB A into LDS (double buffer, row stride 68 dwords = pad 4
// -> uniform bank starts), 2 MFMA sub-steps of 32 k each, ONE barrier.
// B in fragment-order registers, 2 sub-steps ahead (proj5-verified formulas).
__global__ __launch_bounds__(512)
void proj7_kernel(const float* __restrict__ p3, const float* __restrict__ p4,
                  const float* __restrict__ p5,
                  const __half* __restrict__ WF3, const __half* __restrict__ WF4,
                  const __half* __restrict__ WF5,
                  __half* __restrict__ F3, __half* __restrict__ F4,
                  __half* __restrict__ F5,
                  int n5, int n4)
{
    const int bid = blockIdx.x;
    const float* feat; const __half* WF; __half* F;
    int C, HW, m0;
    if (bid < n5)           { C = 2048; HW = 1024;  feat = p5; WF = WF5; F = F5; m0 = bid * 64; }
    else if (bid < n5 + n4) { C = 1024; HW = 4096;  feat = p4; WF = WF4; F = F4; m0 = (bid - n5) * 64; }
    else                    { C = 512;  HW = 16384; feat = p3; WF = WF3; F = F3; m0 = (bid - n5 - n4) * 64; }

    const int tid = threadIdx.x;
    const int wv  = tid >> 6;           // 0..7
    const int l   = tid & 63;
    const int lm  = l & 15;
    const int lg  = l >> 4;             // k-group 0..3 within sub-step
    const int dq  = wv & 3;             // d-quarter (64 d)
    const int ph  = wv >> 2;            // px-half (32 px)
    const int b    = m0 / HW;
    const int pos0 = m0 % HW;
    const int nkk  = C >> 6;            // K-steps of 64 (8/16/32)
    const int nsub = C >> 5;            // sub-steps of 32

    __shared__ float sa[2][64 * 68];    // 2 x 17408 B, 64 rows x (64+4 pad)

    // staging: lane l of wave wv covers px = wv*8 + (l>>3), k = i*8 + (l&7);
    // instr i writes LDS row wv*8 + i (dword lane offset within row = l).
    const float* a_st = feat + (size_t)b * C * HW + pos0
                      + (size_t)(l & 7) * HW + (wv << 3) + (l >> 3);
    const size_t Kstr = (size_t)64 * HW;   // elements per K-step
    const size_t kts  = (size_t)8 * HW;    // elements per k-tile (8 k)

    // B: per-lane fragment base (verified formula)
    const __half* wbase = WF + ((size_t)(dq * 64 + lm) * 4 + lg) * 8;

    // A-fragment LDS read offsets (dwords): row = (px>>3)*8 + u*4 + lg,
    // col = (px&7)*8; sub-step u adds 4*68 = 272.
    const int pxq0 = ph * 32 + lm;
    const int pxq1 = pxq0 + 16;
    const int rb0 = (((pxq0 >> 3) << 3) + lg) * 68 + ((pxq0 & 7) << 3);
    const int rb1 = (((pxq1 >> 3) << 3) + lg) * 68 + ((pxq1 & 7) << 3);

    f32x4 acc[8];
    #pragma unroll
    for (int i = 0; i < 8; ++i) acc[i] = (f32x4){0.f, 0.f, 0.f, 0.f};

    f16x8 bc[4], bn[4];

    // prologue: stage K-step 0; load B sub-steps 0,1
    {
        const float* s = a_st;
        float* d0 = &sa[0][(wv * 8) * 68];
        #pragma unroll
        for (int i = 0; i < 8; ++i) GLD4(s + (size_t)i * kts, d0 + i * 68);
    }
    #pragma unroll
    for (int nt = 0; nt < 4; ++nt) bc[nt] = *(const f16x8*)(wbase + nt * 512);
    #pragma unroll
    for (int nt = 0; nt < 4; ++nt) bn[nt] = *(const f16x8*)(wbase + 8192 + nt * 512);
    __syncthreads();

    for (int T = 0; T < nkk; ++T) {
        const int cur = T & 1;
        if (T + 1 < nkk) {
            const float* s = a_st + (size_t)(T + 1) * Kstr;
            float* d0 = &sa[cur ^ 1][(wv * 8) * 68];
            #pragma unroll
            for (int i = 0; i < 8; ++i) GLD4(s + (size_t)i * kts, d0 + i * 68);
        }
        const float* buf = sa[cur];
        const int s0 = 2 * T;

        // ---- sub-step u=0: consume bc ----
        {
            const float4 va = *(const float4*)(buf + rb0);
            const float4 vb = *(const float4*)(buf + rb0 + 4);
            const float4 vc = *(const float4*)(buf + rb1);
            const float4 vd = *(const float4*)(buf + rb1 + 4);
            f16x8 af0, af1;
            af0[0] = (_Float16)va.x; af0[1] = (_Float16)va.y;
            af0[2] = (_Float16)va.z; af0[3] = (_Float16)va.w;
            af0[4] = (_Float16)vb.x; af0[5] = (_Float16)vb.y;
            af0[6] = (_Float16)vb.z; af0[7] = (_Float16)vb.w;
            af1[0] = (_Float16)vc.x; af1[1] = (_Float16)vc.y;
            af1[2] = (_Float16)vc.z; af1[3] = (_Float16)vc.w;
            af1[4] = (_Float16)vd.x; af1[5] = (_Float16)vd.y;
            af1[6] = (_Float16)vd.z; af1[7] = (_Float16)vd.w;
            #pragma unroll
            for (int nt = 0; nt < 4; ++nt) {
                acc[nt]     = __builtin_amdgcn_mfma_f32_16x16x32_f16(af0, bc[nt], acc[nt],     0, 0, 0);
                acc[nt + 4] = __builtin_amdgcn_mfma_f32_16x16x32_f16(af1, bc[nt], acc[nt + 4], 0, 0, 0);
            }
            if (s0 + 2 < nsub) {
                const __half* wb = wbase + (size_t)(s0 + 2) * 8192;
                #pragma unroll
                for (int nt = 0; nt < 4; ++nt) bc[nt] = *(const f16x8*)(wb + nt * 512);
            }
        }
        // ---- sub-step u=1: consume bn ----
        {
            const float4 va = *(const float4*)(buf + rb0 + 272);
            const float4 vb = *(const float4*)(buf + rb0 + 276);
            const float4 vc = *(const float4*)(buf + rb1 + 272);
            const float4 vd = *(const float4*)(buf + rb1 + 276);
            f16x8 af0, af1;
            af0[0] = (_Float16)va.x; af0[1] = (_Float16)va.y;
            af0[2] = (_Float16)va.z; af0[3] = (_Float16)va.w;
            af0[4] = (_Float16)vb.x; af0[5] = (_Float16)vb.y;
            af0[6] = (_Float16)vb.z; af0[7] = (_Float16)vb.w;
            af1[0] = (_Float16)vc.x; af1[1] = (_Float16)vc.y;
            af1[2] = (_Float16)vc.z; af1[3] = (_Float16)vc.w;
            af1[4] = (_Float16)vd.x; af1[5] = (_Float16)vd.y;
            af1[6] = (_Float16)vd.z; af1[7] = (_Float16)vd.w;
            #pragma unroll
            for (int nt = 0; nt < 4; ++nt) {
                acc[nt]     = __builtin_amdgcn_mfma_f32_16x16x32_f16(af0, bn[nt], acc[nt],     0, 0, 0);
                acc[nt + 4] = __builtin_amdgcn_mfma_f32_16x16x32_f16(af1, bn[nt], acc[nt + 4], 0, 0, 0);
            }
            if (s0 + 3 < nsub) {
                const __half* wb = wbase + (size_t)(s0 + 3) * 8192;
                #pragma unroll
                for (int nt = 0; nt < 4; ++nt) bn[nt] = *(const f16x8*)(wb + nt * 512);
            }
        }
        __syncthreads();
    }

    // store: d = dq*64 + nt*16 + lm (col=lane&15), px row = lg*4 + i
    #pragma unroll
    for (int mt = 0; mt < 2; ++mt) {
        #pragma unroll
        for (int nt = 0; nt < 4; ++nt) {
            #pragma unroll
            for (int i = 0; i < 4; ++i) {
                const int px = pos0 + ph * 32 + mt * 16 + lg * 4 + i;
                const int d  = dq * 64 + nt * 16 + lm;
                F[((size_t)b * HW + px) * 256 + d] = __float2half(acc[nt + mt * 4][i]);
            }
        }
    }
}

// ---- sample2: per (n,s) channel-last bilinear sampling ---------------------
__global__ __launch_bounds__(256)
void sample2_kernel(const __half* __restrict__ F3, const __half* __restrict__ F4,
                    const __half* __restrict__ F5,
                    const float* __restrict__ SREC, const float* __restrict__ P,
                    float* __restrict__ tokp, int K100)
{
    const int n = blockIdx.x;
    const int s = blockIdx.y;
    const int d = threadIdx.x;
    const int b = n / K100;

    __shared__ float rsh[64];
    if (d < 64) rsh[d] = SREC[(size_t)(n * 3 + s) * 64 + d];
    __syncthreads();

    const __half* F; int HW, W;
    if (s == 0)      { F = F3; HW = 16384; W = 128; }
    else if (s == 1) { F = F4; HW = 4096;  W = 64; }
    else             { F = F5; HW = 1024;  W = 32; }

    const int ny = (int)rsh[0];
    const int nx = (int)rsh[1];
    const size_t base = (size_t)b * HW * 256 + d;

    float acc = 0.0f;
    for (int i = 0; i < ny; ++i) {
        const int   row = (int)rsh[4 + i];
        const float wyv = rsh[16 + i];
        const size_t rb = base + (size_t)(row * W) * 256;
        float rsum = 0.0f;
        for (int j = 0; j < nx; ++j) {
            const int   col = (int)rsh[28 + j];
            const float wxv = rsh[40 + j];
            rsum = fmaf(wxv, __half2float(F[rb + (size_t)col * 256]), rsum);
        }
        acc = fmaf(wyv, rsum, acc);
    }
    tokp[(size_t)(n * 3 + s) * 256 + d] = acc * (1.0f / 36.0f)
                                        + P[(size_t)(n * 3 + s) * 256 + d];
}

// ---- mlp2: sum 3 partials, LayerNorm, Linear-GELU-Linear -------------------
__global__ __launch_bounds__(256)
void mlp2_kernel(const float* __restrict__ tokp,
                 const float* __restrict__ lng, const float* __restrict__ lnb,
                 const float* __restrict__ W1T, const float* __restrict__ b1,
                 const float* __restrict__ W2T, const float* __restrict__ b2,
                 float* __restrict__ out, int N)
{
    const int n0  = blockIdx.x * 8;
    const int tid = threadIdx.x;

    __shared__ float tokl[8][257];
    __shared__ float hl[8][257];
    __shared__ float mval[8], rstd[8];

    #pragma unroll
    for (int t = 0; t < 8; ++t) {
        const size_t nb = (size_t)(n0 + t) * 3 * 256 + tid;
        tokl[t][tid] = tokp[nb] + tokp[nb + 256] + tokp[nb + 512];
    }
    __syncthreads();

    const int wv = tid >> 6, lane = tid & 63;
    for (int t = wv; t < 8; t += 4) {
        float x0 = tokl[t][lane], x1 = tokl[t][lane + 64];
        float x2 = tokl[t][lane + 128], x3 = tokl[t][lane + 192];
        float sm = x0 + x1 + x2 + x3;
        float sq = x0 * x0 + x1 * x1 + x2 * x2 + x3 * x3;
        #pragma unroll
        for (int o = 32; o; o >>= 1) { sm += __shfl_xor(sm, o); sq += __shfl_xor(sq, o); }
        if (lane == 0) {
            float m   = sm * (1.0f / 256.0f);
            float var = sq * (1.0f / 256.0f) - m * m;
            mval[t] = m;
            rstd[t] = rsqrtf(var + 1e-5f);
        }
    }
    __syncthreads();

    const float g = lng[tid], be = lnb[tid];
    #pragma unroll
    for (int t = 0; t < 8; ++t)
        hl[t][tid] = (tokl[t][tid] - mval[t]) * rstd[t] * g + be;
    __syncthreads();

    float acc[8];
    const float bb1 = b1[tid];
    #pragma unroll
    for (int t = 0; t < 8; ++t) acc[t] = bb1;
    for (int k = 0; k < 256; ++k) {
        float w = W1T[(size_t)k * 256 + tid];
        #pragma unroll
        for (int t = 0; t < 8; ++t) acc[t] = fmaf(hl[t][k], w, acc[t]);
    }
    __syncthreads();
    #pragma unroll
    for (int t = 0; t < 8; ++t) tokl[t][tid] = gelu_exact(acc[t]);
    __syncthreads();

    const float bb2 = b2[tid];
    #pragma unroll
    for (int t = 0; t < 8; ++t) acc[t] = bb2;
    for (int k = 0; k < 256; ++k) {
        float w = W2T[(size_t)k * 256 + tid];
        #pragma unroll
        for (int t = 0; t < 8; ++t) acc[t] = fmaf(tokl[t][k], w, acc[t]);
    }
    #pragma unroll
    for (int t = 0; t < 8; ++t)
        out[(size_t)(n0 + t) * 256 + tid] = acc[t];
}

// ======================= OLD (fallback) PIPELINE ============================

__global__ __launch_bounds__(256)
void build_wt_kernel(const float* __restrict__ W3, const float* __restrict__ W4,
                     const float* __restrict__ W5, const float* __restrict__ W1,
                     const float* __restrict__ W2,
                     float* __restrict__ WT, float* __restrict__ W1T,
                     float* __restrict__ W2T)
{
    int k = blockIdx.x;
    int d = threadIdx.x;
    if (k < 512)       WT[(size_t)k * 256 + d]          = W3[(size_t)d * 512  + k];
    else if (k < 1536) WT[(size_t)k * 256 + d]          = W4[(size_t)d * 1024 + (k - 512)];
    else if (k < 3584) WT[(size_t)k * 256 + d]          = W5[(size_t)d * 2048 + (k - 1536)];
    else if (k < 3840) W1T[(size_t)(k - 3584) * 256 + d] = W1[(size_t)d * 256 + (k - 3584)];
    else               W2T[(size_t)(k - 3840) * 256 + d] = W2[(size_t)d * 256 + (k - 3840)];
}

__global__ __launch_bounds__(256)
void roi_setup_kernel(const float* __restrict__ boxes,
                      const float* __restrict__ b3, const float* __restrict__ b4,
                      const float* __restrict__ b5,
                      const int* __restrict__ iw_p, const int* __restrict__ ih_p,
                      float* __restrict__ WREC, float* __restrict__ P)
{
    const int n   = blockIdx.x;
    const int s   = blockIdx.y;
    const int tid = threadIdx.x;

    int H, W;
    const float* bp;
    if (s == 0)      { H = 128; W = 128; bp = b3; }
    else if (s == 1) { H = 64;  W = 64;  bp = b4; }
    else             { H = 32;  W = 32;  bp = b5; }

    __shared__ float wy[32];
    __shared__ float wx[48];
    __shared__ int   sh_r0, sh_rs, sh_x0, sh_nc;
    __shared__ float sh_syc, sh_sxc;

    if (tid < 32)                 wy[tid]      = 0.0f;
    if (tid >= 32 && tid < 80)    wx[tid - 32] = 0.0f;
    __syncthreads();

    const float scale = fminf((float)W / ((float)(*iw_p) + 1e-6f),
                              (float)H / ((float)(*ih_p) + 1e-6f));

    if (tid == 0) {
        float c1 = boxes[(size_t)n * 4 + 1] * scale - 0.5f;
        float c2 = boxes[(size_t)n * 4 + 3] * scale - 0.5f;
        float bs = (c2 - c1) / 3.0f;
        int   yls[6], yhs[6], vv[6];
        float lys[6];
        int r0 = INT_MAX; float cnt = 0.0f;
        #pragma unroll
        for (int i = 0; i < 6; ++i) {
            float off = 0.25f + 0.5f * (float)i;
            float ys  = c1 + bs * off;
            int v = (ys >= -1.0f) && (ys <= (float)H);
            float yc = fmaxf(ys, 0.0f);
            int yl = (int)floorf(yc); if (yl > H - 1) yl = H - 1;
            int yh = yl + 1;          if (yh > H - 1) yh = H - 1;
            float ly = yc - (float)yl;
            yls[i] = yl; yhs[i] = yh; lys[i] = ly; vv[i] = v;
            if (v) { r0 = min(r0, yl); cnt += 1.0f; }
        }
        if (r0 == INT_MAX) r0 = 0;
        int rmax = 0;
        #pragma unroll
        for (int i = 0; i < 6; ++i) if (vv[i]) {
            int a = min(yls[i] - r0, 31);
            int h = min(yhs[i] - r0, 31);
            wy[a] += 1.0f - lys[i];
            wy[h] += lys[i];
            rmax = max(rmax, h);
        }
        sh_r0 = r0; sh_rs = rmax + 1; sh_syc = cnt;
    }
    if (tid == 1) {
        float c1 = boxes[(size_t)n * 4 + 0] * scale - 0.5f;
        float c2 = boxes[(size_t)n * 4 + 2] * scale - 0.5f;
        float bs = (c2 - c1) / 3.0f;
        int   xls[6], xhs[6], vv[6];
        float lxs[6];
        int x0r = INT_MAX; float cnt = 0.0f;
        #pragma unroll
        for (int i = 0; i < 6; ++i) {
            float off = 0.25f + 0.5f * (float)i;
            float xs  = c1 + bs * off;
            int v = (xs >= -1.0f) && (xs <= (float)W);
            float xc = fmaxf(xs, 0.0f);
            int xl = (int)floorf(xc); if (xl > W - 1) xl = W - 1;
            int xh = xl + 1;          if (xh > W - 1) xh = W - 1;
            float lx = xc - (float)xl;
            xls[i] = xl; xhs[i] = xh; lxs[i] = lx; vv[i] = v;
            if (v) { x0r = min(x0r, xl); cnt += 1.0f; }
        }
        if (x0r == INT_MAX) x0r = 0;
        int x0 = x0r & ~15;
        int imax = 0;
        #pragma unroll
        for (int i = 0; i < 6; ++i) if (vv[i]) {
            int a = min(xls[i] - x0, 47);
            int h = min(xhs[i] - x0, 47);
            wx[a] += 1.0f - lxs[i];
            wx[h] += lxs[i];
            imax = max(imax, h);
        }
        int nc = imax / 16 + 1;
        int ncmax = (W - x0) >> 4;
        nc = min(nc, ncmax);
        sh_x0 = x0; sh_nc = max(nc, 1); sh_sxc = cnt;
    }
    __syncthreads();

    const int r0 = sh_r0, rs = sh_rs, x0 = sh_x0, nc = sh_nc;

    float* rec = &WREC[(size_t)(n * 3 + s) * 96];
    if (tid < 32)                 rec[tid]      = wy[tid];
    else if (tid < 80)            rec[tid]      = wx[tid - 32];
    else if (tid == 80)           rec[80]       = (float)r0;
    else if (tid == 81)           rec[81]       = (float)rs;
    else if (tid == 82)           rec[82]       = (float)x0;
    else if (tid == 83)           rec[83]       = (float)nc;
    else if (tid == 84)           rec[84]       = sh_syc;
    else if (tid == 85)           rec[85]       = sh_sxc;

    {
        const int d = tid;
        const float syc = sh_syc, sxc = sh_sxc;
        float val;
        if (d < 128) {
            int   t     = d >> 2;
            float invf  = expf(-(float)t * (logf(10000.0f) / 32.0f));
            float istep = 1.0f / (float)(H - 1);
            float sum = 0.0f;
            for (int r = 0; r < rs; ++r) {
                float w = wy[r];
                float ang = (float)(r0 + r) * istep * invf;
                float sn, cs; sincosf(ang, &sn, &cs);
                sum = fmaf(w, (d & 1) ? cs : sn, sum);
            }
            val = sxc * sum;
        } else {
            int   d2    = d - 128;
            int   t     = d2 >> 2;
            float invf  = expf(-(float)t * (logf(10000.0f) / 32.0f));
            float istep = 1.0f / (float)(W - 1);
            float sum = 0.0f;
            int nx = nc << 4;
            for (int j = 0; j < nx; ++j) {
                float w = wx[j];
                if (w != 0.0f) {
                    float ang = (float)(x0 + j) * istep * invf;
                    float sn, cs; sincosf(ang, &sn, &cs);
                    sum = fmaf(w, (d & 1) ? cs : sn, sum);
                }
            }
            val = syc * sum;
        }
        float cnt = syc * sxc;
        P[((size_t)n * 3 + s) * 256 + d] = (val + cnt * bp[d]) * (1.0f / 36.0f);
    }
}

__global__ __launch_bounds__(256)
void roi_gather_kernel(const float* __restrict__ p3, const float* __restrict__ p4,
                       const float* __restrict__ p5,
                       const float* __restrict__ WREC,
                       float* __restrict__ G, int K)
{
    const int yc  = blockIdx.x;
    const int n   = blockIdx.y;
    const int tid = threadIdx.x;

    int s, chunk;
    if (yc < 8)       { s = 0; chunk = yc; }
    else if (yc < 24) { s = 1; chunk = yc - 8; }
    else              { s = 2; chunk = yc - 24; }

    int C, H, W, koff;
    const float* feat;
    if (s == 0)      { C = 512;  H = 128; W = 128; koff = 0;    feat = p3; }
    else if (s == 1) { C = 1024; H = 64;  W = 64;  koff = 512;  feat = p4; }
    else             { C = 2048; H = 32;  W = 32;  koff = 1536; feat = p5; }
    const int HW = H * W;
    const int b  = n / K;

    __shared__ float sh[96];
    if (tid < 96) sh[tid] = WREC[(size_t)(n * 3 + s) * 96 + tid];
    __syncthreads();

    const int r0 = (int)sh[80];
    const int rs = (int)sh[81];
    const int x0 = (int)sh[82];
    const int nc = (int)sh[83];

    const int c    = chunk * 64 + (tid >> 2);
    const int slot = tid & 3;

    const float* fp = feat + (size_t)b * C * HW + (size_t)c * HW
                    + (size_t)r0 * W + x0 + slot * 4;

    float acc = 0.0f;
    for (int ch = 0; ch < nc; ++ch) {
        const float4 wxv = *(const float4*)&sh[32 + (ch << 4) + slot * 4];
        const float* a = fp + (ch << 4);
        float4 ra = make_float4(0.f, 0.f, 0.f, 0.f);
        int r = 0;
        for (; r + 4 <= rs; r += 4) {
            const float4 v0 = *(const float4*)(a + (size_t)(r + 0) * W);
            const float4 v1 = *(const float4*)(a + (size_t)(r + 1) * W);
            const float4 v2 = *(const float4*)(a + (size_t)(r + 2) * W);
            const float4 v3 = *(const float4*)(a + (size_t)(r + 3) * W);
            const float w0 = sh[r], w1 = sh[r + 1], w2 = sh[r + 2], w3 = sh[r + 3];
            ra.x = fmaf(w0, v0.x, ra.x); ra.y = fmaf(w0, v0.y, ra.y);
            ra.z = fmaf(w0, v0.z, ra.z); ra.w = fmaf(w0, v0.w, ra.w);
            ra.x = fmaf(w1, v1.x, ra.x); ra.y = fmaf(w1, v1.y, ra.y);
            ra.z = fmaf(w1, v1.z, ra.z); ra.w = fmaf(w1, v1.w, ra.w);
            ra.x = fmaf(w2, v2.x, ra.x); ra.y = fmaf(w2, v2.y, ra.y);
            ra.z = fmaf(w2, v2.z, ra.z); ra.w = fmaf(w2, v2.w, ra.w);
            ra.x = fmaf(w3, v3.x, ra.x); ra.y = fmaf(w3, v3.y, ra.y);
            ra.z = fmaf(w3, v3.z, ra.z); ra.w = fmaf(w3, v3.w, ra.w);
        }
        for (; r < rs; ++r) {
            const float4 v = *(const float4*)(a + (size_t)r * W);
            const float w = sh[r];
            ra.x = fmaf(w, v.x, ra.x); ra.y = fmaf(w, v.y, ra.y);
            ra.z = fmaf(w, v.z, ra.z); ra.w = fmaf(w, v.w, ra.w);
        }
        float dsum = ra.x * wxv.x + ra.y * wxv.y + ra.z * wxv.z + ra.w * wxv.w;
        acc += dsum;
    }
    acc += __shfl_xor(acc, 1, 4);
    acc += __shfl_xor(acc, 2, 4);
    if (slot == 0)
        G[(size_t)n * 3584 + koff + c] = acc * (1.0f / 36.0f);
}

__global__ __launch_bounds__(256)
void proj_gemm_kernel(const float* __restrict__ G, const float* __restrict__ WT,
                      float* __restrict__ part, int N)
{
    const int n0  = blockIdx.x * 8;
    const int kc  = blockIdx.y;
    const int tid = threadIdx.x;

    __shared__ float gl[8][128];
    float acc[8];
    #pragma unroll
    for (int t = 0; t < 8; ++t) acc[t] = 0.0f;

    const int kbase = kc * 512;
    const int lt  = tid >> 5;
    const int lc  = (tid & 31) * 4;

    for (int sub = 0; sub < 4; ++sub) {
        const float4 g4 = *(const float4*)&G[(size_t)(n0 + lt) * 3584 + kbase + sub * 128 + lc];
        *(float4*)&gl[lt][lc] = g4;
        __syncthreads();
        const float* wtp = &WT[(size_t)(kbase + sub * 128) * 256 + tid];
        #pragma unroll 4
        for (int k = 0; k < 128; ++k) {
            float w = wtp[(size_t)k * 256];
            #pragma unroll
            for (int t = 0; t < 8; ++t) acc[t] = fmaf(gl[t][k], w, acc[t]);
        }
        __syncthreads();
    }
    #pragma unroll
    for (int t = 0; t < 8; ++t)
        part[((size_t)kc * N + n0 + t) * 256 + tid] = acc[t];
}

__global__ __launch_bounds__(256)
void mlp_kernel(const float* __restrict__ part, const float* __restrict__ P,
                const float* __restrict__ lng, const float* __restrict__ lnb,
                const float* __restrict__ W1T, const float* __restrict__ b1,
                const float* __restrict__ W2T, const float* __restrict__ b2,
                float* __restrict__ out, int N)
{
    const int n0  = blockIdx.x * 8;
    const int tid = threadIdx.x;

    __shared__ float tokl[8][257];
    __shared__ float hl[8][257];
    __shared__ float mval[8], rstd[8];

    #pragma unroll
    for (int t = 0; t < 8; ++t) {
        const int n = n0 + t;
        float v = 0.0f;
        #pragma unroll
        for (int c = 0; c < 7; ++c) v += part[((size_t)c * N + n) * 256 + tid];
        #pragma unroll
        for (int s = 0; s < 3; ++s) v += P[((size_t)n * 3 + s) * 256 + tid];
        tokl[t][tid] = v;
    }
    __syncthreads();

    const int wv = tid >> 6, lane = tid & 63;
    for (int t = wv; t < 8; t += 4) {
        float x0 = tokl[t][lane], x1 = tokl[t][lane + 64];
        float x2 = tokl[t][lane + 128], x3 = tokl[t][lane + 192];
        float sm = x0 + x1 + x2 + x3;
        float sq = x0 * x0 + x1 * x1 + x2 * x2 + x3 * x3;
        #pragma unroll
        for (int o = 32; o; o >>= 1) { sm += __shfl_xor(sm, o); sq += __shfl_xor(sq, o); }
        if (lane == 0) {
            float m   = sm * (1.0f / 256.0f);
            float var = sq * (1.0f / 256.0f) - m * m;
            mval[t] = m;
            rstd[t] = rsqrtf(var + 1e-5f);
        }
    }
    __syncthreads();

    const float g = lng[tid], be = lnb[tid];
    #pragma unroll
    for (int t = 0; t < 8; ++t)
        hl[t][tid] = (tokl[t][tid] - mval[t]) * rstd[t] * g + be;
    __syncthreads();

    float acc[8];
    const float bb1 = b1[tid];
    #pragma unroll
    for (int t = 0; t < 8; ++t) acc[t] = bb1;
    for (int k = 0; k < 256; ++k) {
        float w = W1T[(size_t)k * 256 + tid];
        #pragma unroll
        for (int t = 0; t < 8; ++t) acc[t] = fmaf(hl[t][k], w, acc[t]);
    }
    __syncthreads();
    #pragma unroll
    for (int t = 0; t < 8; ++t) tokl[t][tid] = gelu_exact(acc[t]);
    __syncthreads();

    const float bb2 = b2[tid];
    #pragma unroll
    for (int t = 0; t < 8; ++t) acc[t] = bb2;
    for (int k = 0; k < 256; ++k) {
        float w = W2T[(size_t)k * 256 + tid];
        #pragma unroll
        for (int t = 0; t < 8; ++t) acc[t] = fmaf(tokl[t][k], w, acc[t]);
    }
    #pragma unroll
    for (int t = 0; t < 8; ++t)
        out[(size_t)(n0 + t) * 256 + tid] = acc[t];
}

// ---------------------------------------------------------------------------
extern "C" void kernel_launch(void* const* d_in, const int* in_sizes, int n_in,
                              void* d_out, int out_size, void* d_ws, size_t ws_size,
                              hipStream_t stream)
{
    const float* p3    = (const float*)d_in[0];
    const float* p4    = (const float*)d_in[1];
    const float* p5    = (const float*)d_in[2];
    const float* boxes = (const float*)d_in[3];
    const float* W3    = (const float*)d_in[4];
    const float* b3    = (const float*)d_in[5];
    const float* W4    = (const float*)d_in[6];
    const float* b4    = (const float*)d_in[7];
    const float* W5    = (const float*)d_in[8];
    const float* b5    = (const float*)d_in[9];
    const float* lng   = (const float*)d_in[10];
    const float* lnb   = (const float*)d_in[11];
    const float* W1    = (const float*)d_in[12];
    const float* b1    = (const float*)d_in[13];
    const float* W2    = (const float*)d_in[14];
    const float* b2    = (const float*)d_in[15];
    const int*   iw    = (const int*)d_in[16];
    const int*   ih    = (const int*)d_in[17];

    const int B = in_sizes[0] / (512 * 128 * 128);   // 8
    const int N = out_size / 256;                    // 800
    const int K100 = N / B;                          // 100

    float* out = (float*)d_out;

    // ---- new-path workspace layout (bytes) ----
    const size_t szF3   = (size_t)B * 16384 * 256 * 2;
    const size_t szF4   = (size_t)B * 4096  * 256 * 2;
    const size_t szF5   = (size_t)B * 1024  * 256 * 2;
    const size_t szWF   = (size_t)3584 * 256 * 2;
    const size_t szSREC = (size_t)N * 3 * 64 * 4;
    const size_t szP    = (size_t)N * 3 * 256 * 4;
    const size_t szTok  = (size_t)N * 3 * 256 * 4;
    const size_t szWT12 = (size_t)256 * 256 * 4;
    const size_t need_new = szF3 + szF4 + szF5 + szWF + szSREC + szP + szTok + 2 * szWT12;

    if (ws_size >= need_new) {
        char* w = (char*)d_ws;
        __half* F3   = (__half*)w;            w += szF3;
        __half* F4   = (__half*)w;            w += szF4;
        __half* F5   = (__half*)w;            w += szF5;
        __half* WF   = (__half*)w;            w += szWF;
        float*  SREC = (float*)w;             w += szSREC;
        float*  P    = (float*)w;             w += szP;
        float*  tokp = (float*)w;             w += szTok;
        float*  W1T  = (float*)w;             w += szWT12;
        float*  W2T  = (float*)w;             w += szWT12;

        __half* WF3 = WF;                     // 512*256  halves (frag order)
        __half* WF4 = WF + 131072;            // 1024*256
        __half* WF5 = WF + 393216;            // 2048*256

        const int n5 = B * 1024  / 64;        // 128
        const int n4 = B * 4096  / 64;        // 512
        const int n3 = B * 16384 / 64;        // 2048

        build_wt3_kernel<<<960, 256, 0, stream>>>(W3, W4, W5, W1, W2,
                                                  WF3, WF4, WF5, W1T, W2T);
        roi_setup2_kernel<<<dim3(N, 3), 256, 0, stream>>>(boxes, b3, b4, b5, iw, ih, SREC, P);
        proj7_kernel<<<n5 + n4 + n3, 512, 0, stream>>>(p3, p4, p5, WF3, WF4, WF5,
                                                       F3, F4, F5, n5, n4);
        sample2_kernel<<<dim3(N, 3), 256, 0, stream>>>(F3, F4, F5, SREC, P, tokp, K100);
        mlp2_kernel<<<N / 8, 256, 0, stream>>>(tokp, lng, lnb, W1T, b1, W2T, b2, out, N);
    } else {
        // fallback: round-3 pipeline (~22 MB workspace)
        float* G    = (float*)d_ws;
        float* P    = G + (size_t)N * 3584;
        float* WT   = P + (size_t)N * 3 * 256;
        float* W1T  = WT + (size_t)3584 * 256;
        float* W2T  = W1T + (size_t)256 * 256;
        float* part = W2T + (size_t)256 * 256;
        float* WREC = part + (size_t)7 * N * 256;

        build_wt_kernel<<<4096, 256, 0, stream>>>(W3, W4, W5, W1, W2, WT, W1T, W2T);
        roi_setup_kernel<<<dim3(N, 3), 256, 0, stream>>>(boxes, b3, b4, b5, iw, ih, WREC, P);
        roi_gather_kernel<<<dim3(56, N), 256, 0, stream>>>(p3, p4, p5, WREC, G, K100);
        proj_gemm_kernel<<<dim3(N / 8, 7), 256, 0, stream>>>(G, WT, part, N);
        mlp_kernel<<<N / 8, 256, 0, stream>>>(part, P, lng, lnb, W1T, b1, W2T, b2, out, N);
    }
}

// Round 12
// 285.471 us; speedup vs baseline: 1.1958x; 1.1609x over previous
//
#include <hip/hip_runtime.h>
#include <hip/hip_fp16.h>
#include <math.h>

#ifndef INT_MAX
#define INT_MAX 0x7fffffff
#endif

typedef __attribute__((ext_vector_type(8))) _Float16 f16x8;
typedef __attribute__((ext_vector_type(4))) float   f32x4;

// ---------------------------------------------------------------------------
// Round 11 -> 12: proj7's wall was staging delivery (FETCH 240MB @1.27TB/s ==
// kernel time); global_load_lds forced 8x32B-scattered global reads. proj8:
// register staging (1 float4/thread -> 4x256B coalesced transactions/wave),
// ds_write_b128 into k-major [32][68] LDS with XOR col-swizzle
// (col = px ^ 4*(kk>>3)) -> conflict-free writes AND reads. BK=32, double
// buffer, 1 barrier/step. B fragment-ring unchanged (verified).
// ---------------------------------------------------------------------------

__device__ __forceinline__ float gelu_exact(float x) {
    return 0.5f * x * (1.0f + erff(x * 0.70710678118654752f));
}

// ---- build_wt3: W3/4/5 -> fp16 fragment-order WF; transpose W1/W2 ----------
// WF layout (halves): WF[((t*256 + d)*4 + lg)*8 + j] = W[d][t*32 + lg*8 + j]
__global__ __launch_bounds__(256)
void build_wt3_kernel(const float* __restrict__ W3, const float* __restrict__ W4,
                      const float* __restrict__ W5, const float* __restrict__ W1,
                      const float* __restrict__ W2,
                      __half* __restrict__ WF3, __half* __restrict__ WF4,
                      __half* __restrict__ WF5,
                      float* __restrict__ W1T, float* __restrict__ W2T)
{
    const int bidx = blockIdx.x;
    const int tid  = threadIdx.x;
    if (bidx < 448) {
        const int c = bidx * 256 + tid;
        const float* Wsrc; __half* dst; int K, c0;
        if (c < 16384)      { Wsrc = W3; dst = WF3; K = 512;  c0 = c; }
        else if (c < 49152) { Wsrc = W4; dst = WF4; K = 1024; c0 = c - 16384; }
        else                { Wsrc = W5; dst = WF5; K = 2048; c0 = c - 49152; }
        const int t  = c0 >> 10;        // 32-k step
        const int r  = c0 & 1023;
        const int d  = r >> 2;
        const int lg = r & 3;
        const float* src = Wsrc + (size_t)d * K + t * 32 + lg * 8;
        f16x8 hv;
        #pragma unroll
        for (int j = 0; j < 8; ++j) hv[j] = (_Float16)src[j];
        *(f16x8*)(dst + (size_t)c0 * 8) = hv;
    } else if (bidx < 704) {
        const int k = bidx - 448;
        W1T[(size_t)k * 256 + tid] = W1[(size_t)tid * 256 + k];
    } else {
        const int k = bidx - 704;
        W2T[(size_t)k * 256 + tid] = W2[(size_t)tid * 256 + k];
    }
}

// ---- roi_setup2: per (n,s) compressed bilinear weight lists + pos-enc ------
__global__ __launch_bounds__(256)
void roi_setup2_kernel(const float* __restrict__ boxes,
                       const float* __restrict__ b3, const float* __restrict__ b4,
                       const float* __restrict__ b5,
                       const int* __restrict__ iw_p, const int* __restrict__ ih_p,
                       float* __restrict__ SREC, float* __restrict__ P)
{
    const int n   = blockIdx.x;
    const int s   = blockIdx.y;
    const int tid = threadIdx.x;

    int H, W;
    const float* bp;
    if (s == 0)      { H = 128; W = 128; bp = b3; }
    else if (s == 1) { H = 64;  W = 64;  bp = b4; }
    else             { H = 32;  W = 32;  bp = b5; }

    __shared__ float wy[32];
    __shared__ float wx[48];
    __shared__ int   sh_r0, sh_rs, sh_x0, sh_xs;
    __shared__ float sh_syc, sh_sxc;

    if (tid < 32)              wy[tid]      = 0.0f;
    if (tid >= 32 && tid < 80) wx[tid - 32] = 0.0f;
    __syncthreads();

    const float scale = fminf((float)W / ((float)(*iw_p) + 1e-6f),
                              (float)H / ((float)(*ih_p) + 1e-6f));
    float* rec = &SREC[(size_t)(n * 3 + s) * 64];

    if (tid == 0) {
        float c1 = boxes[(size_t)n * 4 + 1] * scale - 0.5f;
        float c2 = boxes[(size_t)n * 4 + 3] * scale - 0.5f;
        float bs = (c2 - c1) / 3.0f;
        int   yls[6], yhs[6], vv[6];
        float lys[6];
        int r0 = INT_MAX; float cnt = 0.0f;
        #pragma unroll
        for (int i = 0; i < 6; ++i) {
            float off = 0.25f + 0.5f * (float)i;
            float ys  = c1 + bs * off;
            int v = (ys >= -1.0f) && (ys <= (float)H);
            float yc = fmaxf(ys, 0.0f);
            int yl = (int)floorf(yc); if (yl > H - 1) yl = H - 1;
            int yh = yl + 1;          if (yh > H - 1) yh = H - 1;
            float ly = yc - (float)yl;
            yls[i] = yl; yhs[i] = yh; lys[i] = ly; vv[i] = v;
            if (v) { r0 = min(r0, yl); cnt += 1.0f; }
        }
        if (r0 == INT_MAX) r0 = 0;
        int rmax = 0;
        #pragma unroll
        for (int i = 0; i < 6; ++i) if (vv[i]) {
            int a = min(yls[i] - r0, 31);
            int h = min(yhs[i] - r0, 31);
            wy[a] += 1.0f - lys[i];
            wy[h] += lys[i];
            rmax = max(rmax, h);
        }
        sh_r0 = r0; sh_rs = rmax + 1; sh_syc = cnt;
        int cntn = 0;
        for (int r = 0; r <= rmax && cntn < 12; ++r) {
            if (wy[r] != 0.0f) {
                rec[4 + cntn]  = (float)(r0 + r);
                rec[16 + cntn] = wy[r];
                ++cntn;
            }
        }
        rec[0] = (float)cntn;
    }
    if (tid == 1) {
        float c1 = boxes[(size_t)n * 4 + 0] * scale - 0.5f;
        float c2 = boxes[(size_t)n * 4 + 2] * scale - 0.5f;
        float bs = (c2 - c1) / 3.0f;
        int   xls[6], xhs[6], vv[6];
        float lxs[6];
        int x0r = INT_MAX; float cnt = 0.0f;
        #pragma unroll
        for (int i = 0; i < 6; ++i) {
            float off = 0.25f + 0.5f * (float)i;
            float xs  = c1 + bs * off;
            int v = (xs >= -1.0f) && (xs <= (float)W);
            float xc = fmaxf(xs, 0.0f);
            int xl = (int)floorf(xc); if (xl > W - 1) xl = W - 1;
            int xh = xl + 1;          if (xh > W - 1) xh = W - 1;
            float lx = xc - (float)xl;
            xls[i] = xl; xhs[i] = xh; lxs[i] = lx; vv[i] = v;
            if (v) { x0r = min(x0r, xl); cnt += 1.0f; }
        }
        if (x0r == INT_MAX) x0r = 0;
        int imax = 0;
        #pragma unroll
        for (int i = 0; i < 6; ++i) if (vv[i]) {
            int a = min(xls[i] - x0r, 47);
            int h = min(xhs[i] - x0r, 47);
            wx[a] += 1.0f - lxs[i];
            wx[h] += lxs[i];
            imax = max(imax, h);
        }
        sh_x0 = x0r; sh_xs = imax + 1; sh_sxc = cnt;
        int cntn = 0;
        for (int j = 0; j <= imax && cntn < 12; ++j) {
            if (wx[j] != 0.0f) {
                rec[28 + cntn] = (float)(x0r + j);
                rec[40 + cntn] = wx[j];
                ++cntn;
            }
        }
        rec[1] = (float)cntn;
    }
    __syncthreads();

    const int r0 = sh_r0, rs = sh_rs, x0 = sh_x0, xsr = sh_xs;

    {
        const int d = tid;
        const float syc = sh_syc, sxc = sh_sxc;
        float val;
        if (d < 128) {
            int   t     = d >> 2;
            float invf  = expf(-(float)t * (logf(10000.0f) / 32.0f));
            float istep = 1.0f / (float)(H - 1);
            float sum = 0.0f;
            for (int r = 0; r < rs; ++r) {
                float w = wy[r];
                if (w != 0.0f) {
                    float ang = (float)(r0 + r) * istep * invf;
                    float sn, cs; sincosf(ang, &sn, &cs);
                    sum = fmaf(w, (d & 1) ? cs : sn, sum);
                }
            }
            val = sxc * sum;
        } else {
            int   d2    = d - 128;
            int   t     = d2 >> 2;
            float invf  = expf(-(float)t * (logf(10000.0f) / 32.0f));
            float istep = 1.0f / (float)(W - 1);
            float sum = 0.0f;
            for (int j = 0; j < xsr; ++j) {
                float w = wx[j];
                if (w != 0.0f) {
                    float ang = (float)(x0 + j) * istep * invf;
                    float sn, cs; sincosf(ang, &sn, &cs);
                    sum = fmaf(w, (d & 1) ? cs : sn, sum);
                }
            }
            val = syc * sum;
        }
        float cnt = syc * sxc;
        P[((size_t)n * 3 + s) * 256 + d] = (val + cnt * bp[d]) * (1.0f / 36.0f);
    }
}

// ---- proj8: dense fp16 MFMA projection, reg-staged coalesced A -------------
// Block = 8 waves (512 thr) = 64 px x 256 d. Wave = 32 px x 64 d. BK = 32,
// double-buffered LDS [32 kk][68 dw] with XOR col swizzle col = px ^ 4*(kk>>3).
// Stage: thread (kk = tid>>4, pxg = tid&15) loads float4 (4 consecutive px of
// channel kk) -> 4 x 256B transactions/wave; ds_write_b128 conflict-free.
// Fragment read: 8 scalar dwords/m-tile, stride 68, conflict-free via swizzle.
__global__ __launch_bounds__(512, 2)
void proj8_kernel(const float* __restrict__ p3, const float* __restrict__ p4,
                  const float* __restrict__ p5,
                  const __half* __restrict__ WF3, const __half* __restrict__ WF4,
                  const __half* __restrict__ WF5,
                  __half* __restrict__ F3, __half* __restrict__ F4,
                  __half* __restrict__ F5,
                  int n5, int n4)
{
    const int bid = blockIdx.x;
    const float* feat; const __half* WF; __half* F;
    int C, HW, m0;
    if (bid < n5)           { C = 2048; HW = 1024;  feat = p5; WF = WF5; F = F5; m0 = bid * 64; }
    else if (bid < n5 + n4) { C = 1024; HW = 4096;  feat = p4; WF = WF4; F = F4; m0 = (bid - n5) * 64; }
    else                    { C = 512;  HW = 16384; feat = p3; WF = WF3; F = F3; m0 = (bid - n5 - n4) * 64; }

    const int tid = threadIdx.x;
    const int wv  = tid >> 6;           // 0..7
    const int l   = tid & 63;
    const int lm  = l & 15;
    const int lg  = l >> 4;             // k-group 0..3
    const int dq  = wv & 3;             // d-quarter (64 d)
    const int ph  = wv >> 2;            // px-half (32 px)
    const int b    = m0 / HW;
    const int pos0 = m0 % HW;
    const int nsub = C >> 5;            // 16/32/64 (always even)

    __shared__ float sa[2][32 * 68];    // 2 x 8704 B

    // staging: thread covers (channel kk, px pxg*4..pxg*4+3)
    const int kk  = tid >> 4;           // 0..31
    const int pxg = tid & 15;           // 0..15
    const float* ag = feat + (size_t)b * C * HW + pos0 + pxg * 4 + (size_t)kk * HW;
    const size_t sstr = (size_t)32 * HW;
    const int wcol = 4 * (pxg ^ (kk >> 3));          // swizzled col base
    const int woff = kk * 68 + wcol;

    // B: per-lane fragment base (verified)
    const __half* wbase = WF + ((size_t)(dq * 64 + lm) * 4 + lg) * 8;

    // A-fragment LDS read bases (dwords): addr(j) = (lg*8+j)*68 + (pxq ^ 4*lg)
    const int pxq0 = ph * 32 + lm;
    const int pxq1 = pxq0 + 16;
    const int rbase0 = lg * 8 * 68 + (pxq0 ^ (4 * lg));
    const int rbase1 = lg * 8 * 68 + (pxq1 ^ (4 * lg));

    f32x4 acc[8];
    #pragma unroll
    for (int i = 0; i < 8; ++i) acc[i] = (f32x4){0.f, 0.f, 0.f, 0.f};

    f16x8 bc[4], bn[4];
    float4 vh;

    // prologue: stage step 0 directly; preload step 1; B[0],B[1]
    {
        const float4 v0 = *(const float4*)ag;
        *(float4*)&sa[0][woff] = v0;
    }
    vh = *(const float4*)(ag + sstr);
    #pragma unroll
    for (int nt = 0; nt < 4; ++nt) bc[nt] = *(const f16x8*)(wbase + nt * 512);
    #pragma unroll
    for (int nt = 0; nt < 4; ++nt) bn[nt] = *(const f16x8*)(wbase + 8192 + nt * 512);
    __syncthreads();

    for (int s = 0; s < nsub; s += 2) {
        // ---- even step s: consume sa[0]+bc; write data(s+1)->sa[1] ----
        {
            *(float4*)&sa[1][woff] = vh;                      // data(s+1) (always valid)
            if (s + 2 < nsub) vh = *(const float4*)(ag + (size_t)(s + 2) * sstr);

            const float* buf = sa[0];
            f16x8 af0, af1;
            #pragma unroll
            for (int j = 0; j < 8; ++j) af0[j] = (_Float16)buf[rbase0 + j * 68];
            #pragma unroll
            for (int j = 0; j < 8; ++j) af1[j] = (_Float16)buf[rbase1 + j * 68];
            #pragma unroll
            for (int nt = 0; nt < 4; ++nt) {
                acc[nt]     = __builtin_amdgcn_mfma_f32_16x16x32_f16(af0, bc[nt], acc[nt],     0, 0, 0);
                acc[nt + 4] = __builtin_amdgcn_mfma_f32_16x16x32_f16(af1, bc[nt], acc[nt + 4], 0, 0, 0);
            }
            if (s + 2 < nsub) {
                const __half* wb = wbase + (size_t)(s + 2) * 8192;
                #pragma unroll
                for (int nt = 0; nt < 4; ++nt) bc[nt] = *(const f16x8*)(wb + nt * 512);
            }
            __syncthreads();
        }
        // ---- odd step s+1: consume sa[1]+bn; write data(s+2)->sa[0] ----
        {
            if (s + 2 < nsub) *(float4*)&sa[0][woff] = vh;
            if (s + 3 < nsub) vh = *(const float4*)(ag + (size_t)(s + 3) * sstr);

            const float* buf = sa[1];
            f16x8 af0, af1;
            #pragma unroll
            for (int j = 0; j < 8; ++j) af0[j] = (_Float16)buf[rbase0 + j * 68];
            #pragma unroll
            for (int j = 0; j < 8; ++j) af1[j] = (_Float16)buf[rbase1 + j * 68];
            #pragma unroll
            for (int nt = 0; nt < 4; ++nt) {
                acc[nt]     = __builtin_amdgcn_mfma_f32_16x16x32_f16(af0, bn[nt], acc[nt],     0, 0, 0);
                acc[nt + 4] = __builtin_amdgcn_mfma_f32_16x16x32_f16(af1, bn[nt], acc[nt + 4], 0, 0, 0);
            }
            if (s + 3 < nsub) {
                const __half* wb = wbase + (size_t)(s + 3) * 8192;
                #pragma unroll
                for (int nt = 0; nt < 4; ++nt) bn[nt] = *(const f16x8*)(wb + nt * 512);
            }
            __syncthreads();
        }
    }

    // store: d = dq*64 + nt*16 + lm (col=lane&15), px row = lg*4 + i
    #pragma unroll
    for (int mt = 0; mt < 2; ++mt) {
        #pragma unroll
        for (int nt = 0; nt < 4; ++nt) {
            #pragma unroll
            for (int i = 0; i < 4; ++i) {
                const int px = pos0 + ph * 32 + mt * 16 + lg * 4 + i;
                const int d  = dq * 64 + nt * 16 + lm;
                F[((size_t)b * HW + px) * 256 + d] = __float2half(acc[nt + mt * 4][i]);
            }
        }
    }
}

// ---- sample2: per (n,s) channel-last bilinear sampling ---------------------
__global__ __launch_bounds__(256)
void sample2_kernel(const __half* __restrict__ F3, const __half* __restrict__ F4,
                    const __half* __restrict__ F5,
                    const float* __restrict__ SREC, const float* __restrict__ P,
                    float* __restrict__ tokp, int K100)
{
    const int n = blockIdx.x;
    const int s = blockIdx.y;
    const int d = threadIdx.x;
    const int b = n / K100;

    __shared__ float rsh[64];
    if (d < 64) rsh[d] = SREC[(size_t)(n * 3 + s) * 64 + d];
    __syncthreads();

    const __half* F; int HW, W;
    if (s == 0)      { F = F3; HW = 16384; W = 128; }
    else if (s == 1) { F = F4; HW = 4096;  W = 64; }
    else             { F = F5; HW = 1024;  W = 32; }

    const int ny = (int)rsh[0];
    const int nx = (int)rsh[1];
    const size_t base = (size_t)b * HW * 256 + d;

    float acc = 0.0f;
    for (int i = 0; i < ny; ++i) {
        const int   row = (int)rsh[4 + i];
        const float wyv = rsh[16 + i];
        const size_t rb = base + (size_t)(row * W) * 256;
        float rsum = 0.0f;
        for (int j = 0; j < nx; ++j) {
            const int   col = (int)rsh[28 + j];
            const float wxv = rsh[40 + j];
            rsum = fmaf(wxv, __half2float(F[rb + (size_t)col * 256]), rsum);
        }
        acc = fmaf(wyv, rsum, acc);
    }
    tokp[(size_t)(n * 3 + s) * 256 + d] = acc * (1.0f / 36.0f)
                                        + P[(size_t)(n * 3 + s) * 256 + d];
}

// ---- mlp2: sum 3 partials, LayerNorm, Linear-GELU-Linear -------------------
__global__ __launch_bounds__(256)
void mlp2_kernel(const float* __restrict__ tokp,
                 const float* __restrict__ lng, const float* __restrict__ lnb,
                 const float* __restrict__ W1T, const float* __restrict__ b1,
                 const float* __restrict__ W2T, const float* __restrict__ b2,
                 float* __restrict__ out, int N)
{
    const int n0  = blockIdx.x * 8;
    const int tid = threadIdx.x;

    __shared__ float tokl[8][257];
    __shared__ float hl[8][257];
    __shared__ float mval[8], rstd[8];

    #pragma unroll
    for (int t = 0; t < 8; ++t) {
        const size_t nb = (size_t)(n0 + t) * 3 * 256 + tid;
        tokl[t][tid] = tokp[nb] + tokp[nb + 256] + tokp[nb + 512];
    }
    __syncthreads();

    const int wv = tid >> 6, lane = tid & 63;
    for (int t = wv; t < 8; t += 4) {
        float x0 = tokl[t][lane], x1 = tokl[t][lane + 64];
        float x2 = tokl[t][lane + 128], x3 = tokl[t][lane + 192];
        float sm = x0 + x1 + x2 + x3;
        float sq = x0 * x0 + x1 * x1 + x2 * x2 + x3 * x3;
        #pragma unroll
        for (int o = 32; o; o >>= 1) { sm += __shfl_xor(sm, o); sq += __shfl_xor(sq, o); }
        if (lane == 0) {
            float m   = sm * (1.0f / 256.0f);
            float var = sq * (1.0f / 256.0f) - m * m;
            mval[t] = m;
            rstd[t] = rsqrtf(var + 1e-5f);
        }
    }
    __syncthreads();

    const float g = lng[tid], be = lnb[tid];
    #pragma unroll
    for (int t = 0; t < 8; ++t)
        hl[t][tid] = (tokl[t][tid] - mval[t]) * rstd[t] * g + be;
    __syncthreads();

    float acc[8];
    const float bb1 = b1[tid];
    #pragma unroll
    for (int t = 0; t < 8; ++t) acc[t] = bb1;
    for (int k = 0; k < 256; ++k) {
        float w = W1T[(size_t)k * 256 + tid];
        #pragma unroll
        for (int t = 0; t < 8; ++t) acc[t] = fmaf(hl[t][k], w, acc[t]);
    }
    __syncthreads();
    #pragma unroll
    for (int t = 0; t < 8; ++t) tokl[t][tid] = gelu_exact(acc[t]);
    __syncthreads();

    const float bb2 = b2[tid];
    #pragma unroll
    for (int t = 0; t < 8; ++t) acc[t] = bb2;
    for (int k = 0; k < 256; ++k) {
        float w = W2T[(size_t)k * 256 + tid];
        #pragma unroll
        for (int t = 0; t < 8; ++t) acc[t] = fmaf(tokl[t][k], w, acc[t]);
    }
    #pragma unroll
    for (int t = 0; t < 8; ++t)
        out[(size_t)(n0 + t) * 256 + tid] = acc[t];
}

// ======================= OLD (fallback) PIPELINE ============================

__global__ __launch_bounds__(256)
void build_wt_kernel(const float* __restrict__ W3, const float* __restrict__ W4,
                     const float* __restrict__ W5, const float* __restrict__ W1,
                     const float* __restrict__ W2,
                     float* __restrict__ WT, float* __restrict__ W1T,
                     float* __restrict__ W2T)
{
    int k = blockIdx.x;
    int d = threadIdx.x;
    if (k < 512)       WT[(size_t)k * 256 + d]          = W3[(size_t)d * 512  + k];
    else if (k < 1536) WT[(size_t)k * 256 + d]          = W4[(size_t)d * 1024 + (k - 512)];
    else if (k < 3584) WT[(size_t)k * 256 + d]          = W5[(size_t)d * 2048 + (k - 1536)];
    else if (k < 3840) W1T[(size_t)(k - 3584) * 256 + d] = W1[(size_t)d * 256 + (k - 3584)];
    else               W2T[(size_t)(k - 3840) * 256 + d] = W2[(size_t)d * 256 + (k - 3840)];
}

__global__ __launch_bounds__(256)
void roi_setup_kernel(const float* __restrict__ boxes,
                      const float* __restrict__ b3, const float* __restrict__ b4,
                      const float* __restrict__ b5,
                      const int* __restrict__ iw_p, const int* __restrict__ ih_p,
                      float* __restrict__ WREC, float* __restrict__ P)
{
    const int n   = blockIdx.x;
    const int s   = blockIdx.y;
    const int tid = threadIdx.x;

    int H, W;
    const float* bp;
    if (s == 0)      { H = 128; W = 128; bp = b3; }
    else if (s == 1) { H = 64;  W = 64;  bp = b4; }
    else             { H = 32;  W = 32;  bp = b5; }

    __shared__ float wy[32];
    __shared__ float wx[48];
    __shared__ int   sh_r0, sh_rs, sh_x0, sh_nc;
    __shared__ float sh_syc, sh_sxc;

    if (tid < 32)                 wy[tid]      = 0.0f;
    if (tid >= 32 && tid < 80)    wx[tid - 32] = 0.0f;
    __syncthreads();

    const float scale = fminf((float)W / ((float)(*iw_p) + 1e-6f),
                              (float)H / ((float)(*ih_p) + 1e-6f));

    if (tid == 0) {
        float c1 = boxes[(size_t)n * 4 + 1] * scale - 0.5f;
        float c2 = boxes[(size_t)n * 4 + 3] * scale - 0.5f;
        float bs = (c2 - c1) / 3.0f;
        int   yls[6], yhs[6], vv[6];
        float lys[6];
        int r0 = INT_MAX; float cnt = 0.0f;
        #pragma unroll
        for (int i = 0; i < 6; ++i) {
            float off = 0.25f + 0.5f * (float)i;
            float ys  = c1 + bs * off;
            int v = (ys >= -1.0f) && (ys <= (float)H);
            float yc = fmaxf(ys, 0.0f);
            int yl = (int)floorf(yc); if (yl > H - 1) yl = H - 1;
            int yh = yl + 1;          if (yh > H - 1) yh = H - 1;
            float ly = yc - (float)yl;
            yls[i] = yl; yhs[i] = yh; lys[i] = ly; vv[i] = v;
            if (v) { r0 = min(r0, yl); cnt += 1.0f; }
        }
        if (r0 == INT_MAX) r0 = 0;
        int rmax = 0;
        #pragma unroll
        for (int i = 0; i < 6; ++i) if (vv[i]) {
            int a = min(yls[i] - r0, 31);
            int h = min(yhs[i] - r0, 31);
            wy[a] += 1.0f - lys[i];
            wy[h] += lys[i];
            rmax = max(rmax, h);
        }
        sh_r0 = r0; sh_rs = rmax + 1; sh_syc = cnt;
    }
    if (tid == 1) {
        float c1 = boxes[(size_t)n * 4 + 0] * scale - 0.5f;
        float c2 = boxes[(size_t)n * 4 + 2] * scale - 0.5f;
        float bs = (c2 - c1) / 3.0f;
        int   xls[6], xhs[6], vv[6];
        float lxs[6];
        int x0r = INT_MAX; float cnt = 0.0f;
        #pragma unroll
        for (int i = 0; i < 6; ++i) {
            float off = 0.25f + 0.5f * (float)i;
            float xs  = c1 + bs * off;
            int v = (xs >= -1.0f) && (xs <= (float)W);
            float xc = fmaxf(xs, 0.0f);
            int xl = (int)floorf(xc); if (xl > W - 1) xl = W - 1;
            int xh = xl + 1;          if (xh > W - 1) xh = W - 1;
            float lx = xc - (float)xl;
            xls[i] = xl; xhs[i] = xh; lxs[i] = lx; vv[i] = v;
            if (v) { x0r = min(x0r, xl); cnt += 1.0f; }
        }
        if (x0r == INT_MAX) x0r = 0;
        int x0 = x0r & ~15;
        int imax = 0;
        #pragma unroll
        for (int i = 0; i < 6; ++i) if (vv[i]) {
            int a = min(xls[i] - x0, 47);
            int h = min(xhs[i] - x0, 47);
            wx[a] += 1.0f - lxs[i];
            wx[h] += lxs[i];
            imax = max(imax, h);
        }
        int nc = imax / 16 + 1;
        int ncmax = (W - x0) >> 4;
        nc = min(nc, ncmax);
        sh_x0 = x0; sh_nc = max(nc, 1); sh_sxc = cnt;
    }
    __syncthreads();

    const int r0 = sh_r0, rs = sh_rs, x0 = sh_x0, nc = sh_nc;

    float* rec = &WREC[(size_t)(n * 3 + s) * 96];
    if (tid < 32)                 rec[tid]      = wy[tid];
    else if (tid < 80)            rec[tid]      = wx[tid - 32];
    else if (tid == 80)           rec[80]       = (float)r0;
    else if (tid == 81)           rec[81]       = (float)rs;
    else if (tid == 82)           rec[82]       = (float)x0;
    else if (tid == 83)           rec[83]       = (float)nc;
    else if (tid == 84)           rec[84]       = sh_syc;
    else if (tid == 85)           rec[85]       = sh_sxc;

    {
        const int d = tid;
        const float syc = sh_syc, sxc = sh_sxc;
        float val;
        if (d < 128) {
            int   t     = d >> 2;
            float invf  = expf(-(float)t * (logf(10000.0f) / 32.0f));
            float istep = 1.0f / (float)(H - 1);
            float sum = 0.0f;
            for (int r = 0; r < rs; ++r) {
                float w = wy[r];
                float ang = (float)(r0 + r) * istep * invf;
                float sn, cs; sincosf(ang, &sn, &cs);
                sum = fmaf(w, (d & 1) ? cs : sn, sum);
            }
            val = sxc * sum;
        } else {
            int   d2    = d - 128;
            int   t     = d2 >> 2;
            float invf  = expf(-(float)t * (logf(10000.0f) / 32.0f));
            float istep = 1.0f / (float)(W - 1);
            float sum = 0.0f;
            int nx = nc << 4;
            for (int j = 0; j < nx; ++j) {
                float w = wx[j];
                if (w != 0.0f) {
                    float ang = (float)(x0 + j) * istep * invf;
                    float sn, cs; sincosf(ang, &sn, &cs);
                    sum = fmaf(w, (d & 1) ? cs : sn, sum);
                }
            }
            val = syc * sum;
        }
        float cnt = syc * sxc;
        P[((size_t)n * 3 + s) * 256 + d] = (val + cnt * bp[d]) * (1.0f / 36.0f);
    }
}

__global__ __launch_bounds__(256)
void roi_gather_kernel(const float* __restrict__ p3, const float* __restrict__ p4,
                       const float* __restrict__ p5,
                       const float* __restrict__ WREC,
                       float* __restrict__ G, int K)
{
    const int yc  = blockIdx.x;
    const int n   = blockIdx.y;
    const int tid = threadIdx.x;

    int s, chunk;
    if (yc < 8)       { s = 0; chunk = yc; }
    else if (yc < 24) { s = 1; chunk = yc - 8; }
    else              { s = 2; chunk = yc - 24; }

    int C, H, W, koff;
    const float* feat;
    if (s == 0)      { C = 512;  H = 128; W = 128; koff = 0;    feat = p3; }
    else if (s == 1) { C = 1024; H = 64;  W = 64;  koff = 512;  feat = p4; }
    else             { C = 2048; H = 32;  W = 32;  koff = 1536; feat = p5; }
    const int HW = H * W;
    const int b  = n / K;

    __shared__ float sh[96];
    if (tid < 96) sh[tid] = WREC[(size_t)(n * 3 + s) * 96 + tid];
    __syncthreads();

    const int r0 = (int)sh[80];
    const int rs = (int)sh[81];
    const int x0 = (int)sh[82];
    const int nc = (int)sh[83];

    const int c    = chunk * 64 + (tid >> 2);
    const int slot = tid & 3;

    const float* fp = feat + (size_t)b * C * HW + (size_t)c * HW
                    + (size_t)r0 * W + x0 + slot * 4;

    float acc = 0.0f;
    for (int ch = 0; ch < nc; ++ch) {
        const float4 wxv = *(const float4*)&sh[32 + (ch << 4) + slot * 4];
        const float* a = fp + (ch << 4);
        float4 ra = make_float4(0.f, 0.f, 0.f, 0.f);
        int r = 0;
        for (; r + 4 <= rs; r += 4) {
            const float4 v0 = *(const float4*)(a + (size_t)(r + 0) * W);
            const float4 v1 = *(const float4*)(a + (size_t)(r + 1) * W);
            const float4 v2 = *(const float4*)(a + (size_t)(r + 2) * W);
            const float4 v3 = *(const float4*)(a + (size_t)(r + 3) * W);
            const float w0 = sh[r], w1 = sh[r + 1], w2 = sh[r + 2], w3 = sh[r + 3];
            ra.x = fmaf(w0, v0.x, ra.x); ra.y = fmaf(w0, v0.y, ra.y);
            ra.z = fmaf(w0, v0.z, ra.z); ra.w = fmaf(w0, v0.w, ra.w);
            ra.x = fmaf(w1, v1.x, ra.x); ra.y = fmaf(w1, v1.y, ra.y);
            ra.z = fmaf(w1, v1.z, ra.z); ra.w = fmaf(w1, v1.w, ra.w);
            ra.x = fmaf(w2, v2.x, ra.x); ra.y = fmaf(w2, v2.y, ra.y);
            ra.z = fmaf(w2, v2.z, ra.z); ra.w = fmaf(w2, v2.w, ra.w);
            ra.x = fmaf(w3, v3.x, ra.x); ra.y = fmaf(w3, v3.y, ra.y);
            ra.z = fmaf(w3, v3.z, ra.z); ra.w = fmaf(w3, v3.w, ra.w);
        }
        for (; r < rs; ++r) {
            const float4 v = *(const float4*)(a + (size_t)r * W);
            const float w = sh[r];
            ra.x = fmaf(w, v.x, ra.x); ra.y = fmaf(w, v.y, ra.y);
            ra.z = fmaf(w, v.z, ra.z); ra.w = fmaf(w, v.w, ra.w);
        }
        float dsum = ra.x * wxv.x + ra.y * wxv.y + ra.z * wxv.z + ra.w * wxv.w;
        acc += dsum;
    }
    acc += __shfl_xor(acc, 1, 4);
    acc += __shfl_xor(acc, 2, 4);
    if (slot == 0)
        G[(size_t)n * 3584 + koff + c] = acc * (1.0f / 36.0f);
}

__global__ __launch_bounds__(256)
void proj_gemm_kernel(const float* __restrict__ G, const float* __restrict__ WT,
                      float* __restrict__ part, int N)
{
    const int n0  = blockIdx.x * 8;
    const int kc  = blockIdx.y;
    const int tid = threadIdx.x;

    __shared__ float gl[8][128];
    float acc[8];
    #pragma unroll
    for (int t = 0; t < 8; ++t) acc[t] = 0.0f;

    const int kbase = kc * 512;
    const int lt  = tid >> 5;
    const int lc  = (tid & 31) * 4;

    for (int sub = 0; sub < 4; ++sub) {
        const float4 g4 = *(const float4*)&G[(size_t)(n0 + lt) * 3584 + kbase + sub * 128 + lc];
        *(float4*)&gl[lt][lc] = g4;
        __syncthreads();
        const float* wtp = &WT[(size_t)(kbase + sub * 128) * 256 + tid];
        #pragma unroll 4
        for (int k = 0; k < 128; ++k) {
            float w = wtp[(size_t)k * 256];
            #pragma unroll
            for (int t = 0; t < 8; ++t) acc[t] = fmaf(gl[t][k], w, acc[t]);
        }
        __syncthreads();
    }
    #pragma unroll
    for (int t = 0; t < 8; ++t)
        part[((size_t)kc * N + n0 + t) * 256 + tid] = acc[t];
}

__global__ __launch_bounds__(256)
void mlp_kernel(const float* __restrict__ part, const float* __restrict__ P,
                const float* __restrict__ lng, const float* __restrict__ lnb,
                const float* __restrict__ W1T, const float* __restrict__ b1,
                const float* __restrict__ W2T, const float* __restrict__ b2,
                float* __restrict__ out, int N)
{
    const int n0  = blockIdx.x * 8;
    const int tid = threadIdx.x;

    __shared__ float tokl[8][257];
    __shared__ float hl[8][257];
    __shared__ float mval[8], rstd[8];

    #pragma unroll
    for (int t = 0; t < 8; ++t) {
        const int n = n0 + t;
        float v = 0.0f;
        #pragma unroll
        for (int c = 0; c < 7; ++c) v += part[((size_t)c * N + n) * 256 + tid];
        #pragma unroll
        for (int s = 0; s < 3; ++s) v += P[((size_t)n * 3 + s) * 256 + tid];
        tokl[t][tid] = v;
    }
    __syncthreads();

    const int wv = tid >> 6, lane = tid & 63;
    for (int t = wv; t < 8; t += 4) {
        float x0 = tokl[t][lane], x1 = tokl[t][lane + 64];
        float x2 = tokl[t][lane + 128], x3 = tokl[t][lane + 192];
        float sm = x0 + x1 + x2 + x3;
        float sq = x0 * x0 + x1 * x1 + x2 * x2 + x3 * x3;
        #pragma unroll
        for (int o = 32; o; o >>= 1) { sm += __shfl_xor(sm, o); sq += __shfl_xor(sq, o); }
        if (lane == 0) {
            float m   = sm * (1.0f / 256.0f);
            float var = sq * (1.0f / 256.0f) - m * m;
            mval[t] = m;
            rstd[t] = rsqrtf(var + 1e-5f);
        }
    }
    __syncthreads();

    const float g = lng[tid], be = lnb[tid];
    #pragma unroll
    for (int t = 0; t < 8; ++t)
        hl[t][tid] = (tokl[t][tid] - mval[t]) * rstd[t] * g + be;
    __syncthreads();

    float acc[8];
    const float bb1 = b1[tid];
    #pragma unroll
    for (int t = 0; t < 8; ++t) acc[t] = bb1;
    for (int k = 0; k < 256; ++k) {
        float w = W1T[(size_t)k * 256 + tid];
        #pragma unroll
        for (int t = 0; t < 8; ++t) acc[t] = fmaf(hl[t][k], w, acc[t]);
    }
    __syncthreads();
    #pragma unroll
    for (int t = 0; t < 8; ++t) tokl[t][tid] = gelu_exact(acc[t]);
    __syncthreads();

    const float bb2 = b2[tid];
    #pragma unroll
    for (int t = 0; t < 8; ++t) acc[t] = bb2;
    for (int k = 0; k < 256; ++k) {
        float w = W2T[(size_t)k * 256 + tid];
        #pragma unroll
        for (int t = 0; t < 8; ++t) acc[t] = fmaf(tokl[t][k], w, acc[t]);
    }
    #pragma unroll
    for (int t = 0; t < 8; ++t)
        out[(size_t)(n0 + t) * 256 + tid] = acc[t];
}

// ---------------------------------------------------------------------------
extern "C" void kernel_launch(void* const* d_in, const int* in_sizes, int n_in,
                              void* d_out, int out_size, void* d_ws, size_t ws_size,
                              hipStream_t stream)
{
    const float* p3    = (const float*)d_in[0];
    const float* p4    = (const float*)d_in[1];
    const float* p5    = (const float*)d_in[2];
    const float* boxes = (const float*)d_in[3];
    const float* W3    = (const float*)d_in[4];
    const float* b3    = (const float*)d_in[5];
    const float* W4    = (const float*)d_in[6];
    const float* b4    = (const float*)d_in[7];
    const float* W5    = (const float*)d_in[8];
    const float* b5    = (const float*)d_in[9];
    const float* lng   = (const float*)d_in[10];
    const float* lnb   = (const float*)d_in[11];
    const float* W1    = (const float*)d_in[12];
    const float* b1    = (const float*)d_in[13];
    const float* W2    = (const float*)d_in[14];
    const float* b2    = (const float*)d_in[15];
    const int*   iw    = (const int*)d_in[16];
    const int*   ih    = (const int*)d_in[17];

    const int B = in_sizes[0] / (512 * 128 * 128);   // 8
    const int N = out_size / 256;                    // 800
    const int K100 = N / B;                          // 100

    float* out = (float*)d_out;

    // ---- new-path workspace layout (bytes) ----
    const size_t szF3   = (size_t)B * 16384 * 256 * 2;
    const size_t szF4   = (size_t)B * 4096  * 256 * 2;
    const size_t szF5   = (size_t)B * 1024  * 256 * 2;
    const size_t szWF   = (size_t)3584 * 256 * 2;
    const size_t szSREC = (size_t)N * 3 * 64 * 4;
    const size_t szP    = (size_t)N * 3 * 256 * 4;
    const size_t szTok  = (size_t)N * 3 * 256 * 4;
    const size_t szWT12 = (size_t)256 * 256 * 4;
    const size_t need_new = szF3 + szF4 + szF5 + szWF + szSREC + szP + szTok + 2 * szWT12;

    if (ws_size >= need_new) {
        char* w = (char*)d_ws;
        __half* F3   = (__half*)w;            w += szF3;
        __half* F4   = (__half*)w;            w += szF4;
        __half* F5   = (__half*)w;            w += szF5;
        __half* WF   = (__half*)w;            w += szWF;
        float*  SREC = (float*)w;             w += szSREC;
        float*  P    = (float*)w;             w += szP;
        float*  tokp = (float*)w;             w += szTok;
        float*  W1T  = (float*)w;             w += szWT12;
        float*  W2T  = (float*)w;             w += szWT12;

        __half* WF3 = WF;                     // 512*256  halves (frag order)
        __half* WF4 = WF + 131072;            // 1024*256
        __half* WF5 = WF + 393216;            // 2048*256

        const int n5 = B * 1024  / 64;        // 128
        const int n4 = B * 4096  / 64;        // 512
        const int n3 = B * 16384 / 64;        // 2048

        build_wt3_kernel<<<960, 256, 0, stream>>>(W3, W4, W5, W1, W2,
                                                  WF3, WF4, WF5, W1T, W2T);
        roi_setup2_kernel<<<dim3(N, 3), 256, 0, stream>>>(boxes, b3, b4, b5, iw, ih, SREC, P);
        proj8_kernel<<<n5 + n4 + n3, 512, 0, stream>>>(p3, p4, p5, WF3, WF4, WF5,
                                                       F3, F4, F5, n5, n4);
        sample2_kernel<<<dim3(N, 3), 256, 0, stream>>>(F3, F4, F5, SREC, P, tokp, K100);
        mlp2_kernel<<<N / 8, 256, 0, stream>>>(tokp, lng, lnb, W1T, b1, W2T, b2, out, N);
    } else {
        // fallback: round-3 pipeline (~22 MB workspace)
        float* G    = (float*)d_ws;
        float* P    = G + (size_t)N * 3584;
        float* WT   = P + (size_t)N * 3 * 256;
        float* W1T  = WT + (size_t)3584 * 256;
        float* W2T  = W1T + (size_t)256 * 256;
        float* part = W2T + (size_t)256 * 256;
        float* WREC = part + (size_t)7 * N * 256;

        build_wt_kernel<<<4096, 256, 0, stream>>>(W3, W4, W5, W1, W2, WT, W1T, W2T);
        roi_setup_kernel<<<dim3(N, 3), 256, 0, stream>>>(boxes, b3, b4, b5, iw, ih, WREC, P);
        roi_gather_kernel<<<dim3(56, N), 256, 0, stream>>>(p3, p4, p5, WREC, G, K100);
        proj_gemm_kernel<<<dim3(N / 8, 7), 256, 0, stream>>>(G, WT, part, N);
        mlp_kernel<<<N / 8, 256, 0, stream>>>(part, P, lng, lnb, W1T, b1, W2T, b2, out, N);
    }
}